// Round 6
// baseline (131.447 us; speedup 1.0000x reference)
//
#include <hip/hip_runtime.h>
#include <hip/hip_bf16.h>

typedef short bf16x8 __attribute__((ext_vector_type(8)));
typedef float f32x4 __attribute__((ext_vector_type(4)));

#define N_USER 50000
#define N_ITEM 50000
#define IN_DIM 256
#define HID 128
#define OUT_DIM 64
#define NEDGE 200000
#define CAP 32
#define NSTRIP 3125   // 50000/16

__device__ __forceinline__ float bf2f(unsigned short u) {
    union { unsigned int i; float f; } v; v.i = ((unsigned int)u) << 16; return v.f;
}
__device__ __forceinline__ unsigned short f2bf(float f) {
    union { float f; unsigned int i; } v; v.f = f;
    return (unsigned short)((v.i + 0x7fffu + ((v.i >> 16) & 1u)) >> 16);
}
__device__ __forceinline__ unsigned int cvt_pk_bf16(float a, float b) {
    unsigned int r;
    asm("v_cvt_pk_bf16_f32 %0, %1, %2" : "=v"(r) : "v"(a), "v"(b));
    return r;
}
__device__ __forceinline__ float elu_f(float x) {
    return x > 0.f ? x : (__expf(x) - 1.f);
}

// ---- pack weights into MFMA B-fragment order (bf16), once per launch ----
// Wpk[((nt*8+kb)*64+lane)*8 + j] = bf16(W_proj[(kb*32+kg*8+j)][nt*16+r]), lane=kg*16+r
// Wok[((nt*4+kb)*64+lane)*8 + j] = bf16(W_out [(kb*32+kg*8+j)][nt*16+r])
__global__ __launch_bounds__(256) void pack_w_kernel(
    const float* __restrict__ Wp, const float* __restrict__ Wo,
    unsigned short* __restrict__ Wpk, unsigned short* __restrict__ Wok)
{
    int t = blockIdx.x * 256 + threadIdx.x;
    if (t < 4096) {
        int lane = t & 63, kb = (t >> 6) & 7, nt = t >> 9;
        int r = lane & 15, kg = lane >> 4;
        unsigned short o[8];
        #pragma unroll
        for (int j = 0; j < 8; ++j)
            o[j] = f2bf(Wp[(size_t)(kb * 32 + kg * 8 + j) * HID + nt * 16 + r]);
        #pragma unroll
        for (int j = 0; j < 8; ++j) Wpk[t * 8 + j] = o[j];
    } else if (t < 4096 + 1024) {
        int q = t - 4096;
        int lane = q & 63, kb = (q >> 6) & 3, nt = q >> 8;
        int r = lane & 15, kg = lane >> 4;
        unsigned short o[8];
        #pragma unroll
        for (int j = 0; j < 8; ++j)
            o[j] = f2bf(Wo[(size_t)(kb * 32 + kg * 8 + j) * OUT_DIM + nt * 16 + r]);
        #pragma unroll
        for (int j = 0; j < 8; ++j) Wok[q * 8 + j] = o[j];
    }
}

// Fused projection, no LDS: B-frags read coalesced from packed Wpk (L2-resident 64KB).
// One wave per 16-row strip; strips [0,3125) users, [3125,6250) items.
__global__ __launch_bounds__(256, 6) void proj_kernel(
    const float* __restrict__ x_u, const float* __restrict__ x_i,
    const unsigned short* __restrict__ Wpk, const float* __restrict__ b,
    unsigned short* __restrict__ h_u, unsigned short* __restrict__ h_i)
{
    int wid  = threadIdx.x >> 6;
    int lane = threadIdx.x & 63;
    int strip = blockIdx.x * 4 + wid;
    if (strip >= 2 * NSTRIP) return;
    const float* x = x_u;
    unsigned short* h = h_u;
    if (strip >= NSTRIP) { strip -= NSTRIP; x = x_i; h = h_i; }

    int row0 = strip * 16;
    int r  = lane & 15;
    int kg = lane >> 4;

    // A frags: x[row0+r][kb*32+kg*8 ..], f32->bf16 via packed cvt
    bf16x8 a[8];
    const float* xrow = x + (size_t)(row0 + r) * IN_DIM;
    #pragma unroll
    for (int kb = 0; kb < 8; ++kb) {
        float4 v0 = *(const float4*)(xrow + kb * 32 + kg * 8);
        float4 v1 = *(const float4*)(xrow + kb * 32 + kg * 8 + 4);
        unsigned int* au = (unsigned int*)&a[kb];
        au[0] = cvt_pk_bf16(v0.x, v0.y);
        au[1] = cvt_pk_bf16(v0.z, v0.w);
        au[2] = cvt_pk_bf16(v1.x, v1.y);
        au[3] = cvt_pk_bf16(v1.z, v1.w);
    }

    const bf16x8* wf = (const bf16x8*)Wpk + lane;  // frag stride 64
    #pragma unroll
    for (int nt = 0; nt < 8; ++nt) {
        f32x4 c = {0.f, 0.f, 0.f, 0.f};
        #pragma unroll
        for (int kb = 0; kb < 8; ++kb) {
            bf16x8 bf = wf[(nt * 8 + kb) * 64];
            c = __builtin_amdgcn_mfma_f32_16x16x32_bf16(a[kb], bf, c, 0, 0, 0);
        }
        float bias = b[nt * 16 + r];
        #pragma unroll
        for (int i = 0; i < 4; ++i) {
            int rr = row0 + kg * 4 + i;  // C/D: row=(lane>>4)*4+reg, col=lane&15
            h[(size_t)rr * HID + nt * 16 + r] = f2bf(c[i] + bias);
        }
    }
}

// bucket fill: one thread per edge; slot = atomicAdd(cnt[dst]); bucket[dst*CAP+slot]=src
__global__ __launch_bounds__(256) void fill_kernel(
    const int* __restrict__ e_uu, const int* __restrict__ e_iu, const int* __restrict__ e_ui,
    int* __restrict__ cnt, int* __restrict__ bkt)
{
    int rel = blockIdx.y;
    const int* e = rel == 0 ? e_uu : (rel == 1 ? e_iu : e_ui);
    int g = blockIdx.x * 256 + threadIdx.x;
    if (g >= NEDGE) return;
    int2 sd = *(const int2*)(e + 2 * (size_t)g);
    int* c = cnt + (size_t)rel * N_USER;
    int* bk = bkt + (size_t)rel * N_USER * CAP;
    int slot = atomicAdd(&c[sd.y], 1);
    if (slot < CAP) bk[(size_t)sd.y * CAP + slot] = sd.x;
}

// user gather: one wave per dst user v; 8 predicated independent row loads per relation
__global__ __launch_bounds__(256) void gather_user_kernel(
    const unsigned short* __restrict__ h_u, const unsigned short* __restrict__ h_i,
    const int* __restrict__ cnt, const int* __restrict__ bkt,
    const float* __restrict__ al_uu, const float* __restrict__ ar_uu,
    const float* __restrict__ al_iu, const float* __restrict__ ar_iu,
    unsigned short* __restrict__ g_u)
{
    int v = blockIdx.x * 4 + (threadIdx.x >> 6);
    if (v >= N_USER) return;
    int lane = threadIdx.x & 63;

    unsigned int hv = *(const unsigned int*)(h_u + (size_t)v * HID + lane * 2);

    int d_uu = cnt[v];
    int d_iu = cnt[N_USER + v];

    const int4* b0 = (const int4*)(bkt + (size_t)v * CAP);
    const int4* b1 = (const int4*)(bkt + (size_t)N_USER * CAP + (size_t)v * CAP);
    int4 q0a = b0[0], q0b = b0[1];
    int4 q1a = b1[0], q1b = b1[1];
    int idx0[8] = {q0a.x, q0a.y, q0a.z, q0a.w, q0b.x, q0b.y, q0b.z, q0b.w};
    int idx1[8] = {q1a.x, q1a.y, q1a.z, q1a.w, q1b.x, q1b.y, q1b.z, q1b.w};

    float s0u = 0.f, s1u = 0.f, s0i = 0.f, s1i = 0.f;
    unsigned int ru[8], ri[8];
    #pragma unroll
    for (int j = 0; j < 8; ++j) {
        int s = j < d_uu ? idx0[j] : v;
        ru[j] = *(const unsigned int*)(h_u + (size_t)s * HID + lane * 2);
    }
    #pragma unroll
    for (int j = 0; j < 8; ++j) {
        int s = j < d_iu ? idx1[j] : v;
        ri[j] = *(const unsigned int*)(h_i + (size_t)s * HID + lane * 2);
    }
    #pragma unroll
    for (int j = 0; j < 8; ++j) {
        float mu = j < d_uu ? 1.f : 0.f;
        float mi = j < d_iu ? 1.f : 0.f;
        s0u += mu * bf2f((unsigned short)ru[j]);
        s1u += mu * bf2f((unsigned short)(ru[j] >> 16));
        s0i += mi * bf2f((unsigned short)ri[j]);
        s1i += mi * bf2f((unsigned short)(ri[j] >> 16));
    }
    if (d_uu > 8) {
        int n = min(d_uu, CAP);
        const int* bq = bkt + (size_t)v * CAP;
        for (int j = 8; j < n; ++j) {
            unsigned int u = *(const unsigned int*)(h_u + (size_t)bq[j] * HID + lane * 2);
            s0u += bf2f((unsigned short)u);
            s1u += bf2f((unsigned short)(u >> 16));
        }
    }
    if (d_iu > 8) {
        int n = min(d_iu, CAP);
        const int* bq = bkt + (size_t)N_USER * CAP + (size_t)v * CAP;
        for (int j = 8; j < n; ++j) {
            unsigned int u = *(const unsigned int*)(h_i + (size_t)bq[j] * HID + lane * 2);
            s0i += bf2f((unsigned short)u);
            s1i += bf2f((unsigned short)(u >> 16));
        }
    }

    float rscale = ar_uu[0] * (float)d_uu + ar_iu[0] * (float)d_iu;
    float acc0 = al_uu[0] * s0u + al_iu[0] * s0i + rscale * bf2f((unsigned short)hv);
    float acc1 = al_uu[0] * s1u + al_iu[0] * s1i + rscale * bf2f((unsigned short)(hv >> 16));

    *(unsigned int*)(g_u + (size_t)v * HID + lane * 2) = cvt_pk_bf16(elu_f(acc0), elu_f(acc1));
}

// item gather: one wave per dst item v; writes final f32 out_i row (ELU applied)
__global__ __launch_bounds__(256) void gather_item_kernel(
    const unsigned short* __restrict__ h_u, const unsigned short* __restrict__ h_i,
    const int* __restrict__ cnt, const int* __restrict__ bkt,
    const float* __restrict__ al_ui, const float* __restrict__ ar_ui,
    float* __restrict__ out_i)
{
    int v = blockIdx.x * 4 + (threadIdx.x >> 6);
    if (v >= N_ITEM) return;
    int lane = threadIdx.x & 63;

    unsigned int hv = *(const unsigned int*)(h_i + (size_t)v * HID + lane * 2);

    int d = cnt[2 * N_USER + v];
    const int4* bq4 = (const int4*)(bkt + 2 * (size_t)N_USER * CAP + (size_t)v * CAP);
    int4 qa = bq4[0], qb = bq4[1];
    int idx[8] = {qa.x, qa.y, qa.z, qa.w, qb.x, qb.y, qb.z, qb.w};

    unsigned int rr[8];
    #pragma unroll
    for (int j = 0; j < 8; ++j) {
        int s = j < d ? idx[j] : v;
        rr[j] = *(const unsigned int*)(h_u + (size_t)s * HID + lane * 2);
    }
    float s0 = 0.f, s1 = 0.f;
    #pragma unroll
    for (int j = 0; j < 8; ++j) {
        float m = j < d ? 1.f : 0.f;
        s0 += m * bf2f((unsigned short)rr[j]);
        s1 += m * bf2f((unsigned short)(rr[j] >> 16));
    }
    if (d > 8) {
        int n = min(d, CAP);
        const int* bq = bkt + 2 * (size_t)N_USER * CAP + (size_t)v * CAP;
        for (int j = 8; j < n; ++j) {
            unsigned int u = *(const unsigned int*)(h_u + (size_t)bq[j] * HID + lane * 2);
            s0 += bf2f((unsigned short)u);
            s1 += bf2f((unsigned short)(u >> 16));
        }
    }

    float rscale = ar_ui[0] * (float)d;
    float2 o;
    o.x = elu_f(rscale * bf2f((unsigned short)hv) + al_ui[0] * s0);
    o.y = elu_f(rscale * bf2f((unsigned short)(hv >> 16)) + al_ui[0] * s1);
    *(float2*)(out_i + (size_t)v * HID + lane * 2) = o;
}

// out_u = g_u @ W_out + b_out ; B-frags from packed Wok (coalesced, L2-resident)
__global__ __launch_bounds__(256) void out_user_kernel(
    const unsigned short* __restrict__ g_u, const unsigned short* __restrict__ Wok,
    const float* __restrict__ bo, float* __restrict__ out, int M)
{
    int wid  = threadIdx.x >> 6;
    int lane = threadIdx.x & 63;
    int row0 = (blockIdx.x * 4 + wid) * 16;
    if (row0 >= M) return;

    int r  = lane & 15;
    int kg = lane >> 4;

    bf16x8 a[4];
    const unsigned short* grow = g_u + (size_t)(row0 + r) * HID;
    #pragma unroll
    for (int kb = 0; kb < 4; ++kb)
        a[kb] = *(const bf16x8*)(grow + kb * 32 + kg * 8);

    const bf16x8* wf = (const bf16x8*)Wok + lane;  // frag stride 64
    #pragma unroll
    for (int nt = 0; nt < 4; ++nt) {
        f32x4 c = {0.f, 0.f, 0.f, 0.f};
        #pragma unroll
        for (int kb = 0; kb < 4; ++kb) {
            bf16x8 bf = wf[(nt * 4 + kb) * 64];
            c = __builtin_amdgcn_mfma_f32_16x16x32_bf16(a[kb], bf, c, 0, 0, 0);
        }
        float bias = bo[nt * 16 + r];
        #pragma unroll
        for (int i = 0; i < 4; ++i)
            out[(size_t)(row0 + kg * 4 + i) * OUT_DIM + nt * 16 + r] = c[i] + bias;
    }
}

extern "C" void kernel_launch(void* const* d_in, const int* in_sizes, int n_in,
                              void* d_out, int out_size, void* d_ws, size_t ws_size,
                              hipStream_t stream)
{
    const float* x_user = (const float*)d_in[0];
    const float* x_item = (const float*)d_in[1];
    const float* W_proj = (const float*)d_in[2];
    const float* b_proj = (const float*)d_in[3];
    const float* al_uu  = (const float*)d_in[4];
    const float* ar_uu  = (const float*)d_in[5];
    const float* al_iu  = (const float*)d_in[6];
    const float* ar_iu  = (const float*)d_in[7];
    const float* al_ui  = (const float*)d_in[8];
    const float* ar_ui  = (const float*)d_in[9];
    const float* W_out  = (const float*)d_in[10];
    const float* b_out  = (const float*)d_in[11];
    const int* edges_uu = (const int*)d_in[12];
    const int* edges_iu = (const int*)d_in[13];
    const int* edges_ui = (const int*)d_in[14];

    char* ws = (char*)d_ws;
    unsigned short* h_u = (unsigned short*)(ws);                   // 12,800,000
    unsigned short* h_i = (unsigned short*)(ws + 12800000);        // 12,800,000
    unsigned short* g_u = (unsigned short*)(ws + 25600000);        // 12,800,000
    unsigned short* Wpk = (unsigned short*)(ws + 38400000);        //     65,536
    unsigned short* Wok = (unsigned short*)(ws + 38465536);        //     16,384
    int* cnt            = (int*)(ws + 38481920);                   //    600,000 (3 x 50000)
    int* bkt            = (int*)(ws + 39081920);                   // 19,200,000 (3 x 50000 x 32)

    float* out_u = (float*)d_out;
    float* out_i = out_u + (size_t)N_USER * OUT_DIM;

    hipMemsetAsync(cnt, 0, 3 * N_USER * sizeof(int), stream);

    dim3 blk(256);
    pack_w_kernel<<<dim3(20), blk, 0, stream>>>(W_proj, W_out, Wpk, Wok);

    proj_kernel<<<dim3(1563), blk, 0, stream>>>(x_user, x_item, Wpk, b_proj, h_u, h_i);

    fill_kernel<<<dim3(782, 3), blk, 0, stream>>>(edges_uu, edges_iu, edges_ui, cnt, bkt);

    gather_user_kernel<<<dim3(12500), blk, 0, stream>>>(h_u, h_i, cnt, bkt,
                                                        al_uu, ar_uu, al_iu, ar_iu, g_u);
    gather_item_kernel<<<dim3(12500), blk, 0, stream>>>(h_u, h_i, cnt, bkt,
                                                        al_ui, ar_ui, out_i);

    out_user_kernel<<<dim3(782), blk, 0, stream>>>(g_u, Wok, b_out, out_u, N_USER);
}

// Round 7
// 129.632 us; speedup vs baseline: 1.0140x; 1.0140x over previous
//
#include <hip/hip_runtime.h>
#include <hip/hip_bf16.h>

typedef short bf16x8 __attribute__((ext_vector_type(8)));
typedef float f32x4 __attribute__((ext_vector_type(4)));

#define N_USER 50000
#define N_ITEM 50000
#define IN_DIM 256
#define HID 128
#define OUT_DIM 64
#define NEDGE 200000
#define CAP 32
#define NSTRIP 3125   // 50000/16

__device__ __forceinline__ float bf2f(unsigned short u) {
    union { unsigned int i; float f; } v; v.i = ((unsigned int)u) << 16; return v.f;
}
__device__ __forceinline__ unsigned short f2bf(float f) {
    union { float f; unsigned int i; } v; v.f = f;
    return (unsigned short)((v.i + 0x7fffu + ((v.i >> 16) & 1u)) >> 16);
}
__device__ __forceinline__ unsigned int cvt_pk_bf16(float a, float b) {
    unsigned int r;
    asm("v_cvt_pk_bf16_f32 %0, %1, %2" : "=v"(r) : "v"(a), "v"(b));
    return r;
}
__device__ __forceinline__ float elu_f(float x) {
    return x > 0.f ? x : (__expf(x) - 1.f);
}

// ---- pack weights into MFMA B-fragment order (bf16), once per launch ----
// Wpk[((nt*8+kb)*64+lane)*8 + j] = bf16(W_proj[(kb*32+kg*8+j)][nt*16+r]), lane=kg*16+r
// Wok[((nt*4+kb)*64+lane)*8 + j] = bf16(W_out [(kb*32+kg*8+j)][nt*16+r])
__global__ __launch_bounds__(256) void pack_w_kernel(
    const float* __restrict__ Wp, const float* __restrict__ Wo,
    unsigned short* __restrict__ Wpk, unsigned short* __restrict__ Wok)
{
    int t = blockIdx.x * 256 + threadIdx.x;
    if (t < 4096) {
        int lane = t & 63, kb = (t >> 6) & 7, nt = t >> 9;
        int r = lane & 15, kg = lane >> 4;
        unsigned short o[8];
        #pragma unroll
        for (int j = 0; j < 8; ++j)
            o[j] = f2bf(Wp[(size_t)(kb * 32 + kg * 8 + j) * HID + nt * 16 + r]);
        #pragma unroll
        for (int j = 0; j < 8; ++j) Wpk[t * 8 + j] = o[j];
    } else if (t < 4096 + 1024) {
        int q = t - 4096;
        int lane = q & 63, kb = (q >> 6) & 3, nt = q >> 8;
        int r = lane & 15, kg = lane >> 4;
        unsigned short o[8];
        #pragma unroll
        for (int j = 0; j < 8; ++j)
            o[j] = f2bf(Wo[(size_t)(kb * 32 + kg * 8 + j) * OUT_DIM + nt * 16 + r]);
        #pragma unroll
        for (int j = 0; j < 8; ++j) Wok[q * 8 + j] = o[j];
    }
}

// Fused projection, no LDS: B-frags read coalesced from packed Wpk (L2-resident 64KB).
// One wave per 16-row strip; strips [0,3125) users, [3125,6250) items.
// launch_bounds (256,4): VGPR cap 128 — the a[8] A-fragment set (32 VGPRs) must stay
// in registers; (256,6) in round 6 capped VGPR at 28 and spilled to scratch (50MB HBM).
__global__ __launch_bounds__(256, 4) void proj_kernel(
    const float* __restrict__ x_u, const float* __restrict__ x_i,
    const unsigned short* __restrict__ Wpk, const float* __restrict__ b,
    unsigned short* __restrict__ h_u, unsigned short* __restrict__ h_i)
{
    int wid  = threadIdx.x >> 6;
    int lane = threadIdx.x & 63;
    int strip = blockIdx.x * 4 + wid;
    if (strip >= 2 * NSTRIP) return;
    const float* x = x_u;
    unsigned short* h = h_u;
    if (strip >= NSTRIP) { strip -= NSTRIP; x = x_i; h = h_i; }

    int row0 = strip * 16;
    int r  = lane & 15;
    int kg = lane >> 4;

    // A frags: x[row0+r][kb*32+kg*8 ..], f32->bf16 via packed cvt
    bf16x8 a[8];
    const float* xrow = x + (size_t)(row0 + r) * IN_DIM;
    #pragma unroll
    for (int kb = 0; kb < 8; ++kb) {
        float4 v0 = *(const float4*)(xrow + kb * 32 + kg * 8);
        float4 v1 = *(const float4*)(xrow + kb * 32 + kg * 8 + 4);
        unsigned int* au = (unsigned int*)&a[kb];
        au[0] = cvt_pk_bf16(v0.x, v0.y);
        au[1] = cvt_pk_bf16(v0.z, v0.w);
        au[2] = cvt_pk_bf16(v1.x, v1.y);
        au[3] = cvt_pk_bf16(v1.z, v1.w);
    }

    const bf16x8* wf = (const bf16x8*)Wpk + lane;  // frag stride 64
    #pragma unroll
    for (int nt = 0; nt < 8; ++nt) {
        f32x4 c = {0.f, 0.f, 0.f, 0.f};
        #pragma unroll
        for (int kb = 0; kb < 8; ++kb) {
            bf16x8 bf = wf[(nt * 8 + kb) * 64];
            c = __builtin_amdgcn_mfma_f32_16x16x32_bf16(a[kb], bf, c, 0, 0, 0);
        }
        float bias = b[nt * 16 + r];
        #pragma unroll
        for (int i = 0; i < 4; ++i) {
            int rr = row0 + kg * 4 + i;  // C/D: row=(lane>>4)*4+reg, col=lane&15
            h[(size_t)rr * HID + nt * 16 + r] = f2bf(c[i] + bias);
        }
    }
}

// bucket fill: one thread per edge; slot = atomicAdd(cnt[dst]); bucket[dst*CAP+slot]=src
__global__ __launch_bounds__(256) void fill_kernel(
    const int* __restrict__ e_uu, const int* __restrict__ e_iu, const int* __restrict__ e_ui,
    int* __restrict__ cnt, int* __restrict__ bkt)
{
    int rel = blockIdx.y;
    const int* e = rel == 0 ? e_uu : (rel == 1 ? e_iu : e_ui);
    int g = blockIdx.x * 256 + threadIdx.x;
    if (g >= NEDGE) return;
    int2 sd = *(const int2*)(e + 2 * (size_t)g);
    int* c = cnt + (size_t)rel * N_USER;
    int* bk = bkt + (size_t)rel * N_USER * CAP;
    int slot = atomicAdd(&c[sd.y], 1);
    if (slot < CAP) bk[(size_t)sd.y * CAP + slot] = sd.x;
}

// user gather: one wave per dst user v; 8 predicated independent row loads per relation
__global__ __launch_bounds__(256) void gather_user_kernel(
    const unsigned short* __restrict__ h_u, const unsigned short* __restrict__ h_i,
    const int* __restrict__ cnt, const int* __restrict__ bkt,
    const float* __restrict__ al_uu, const float* __restrict__ ar_uu,
    const float* __restrict__ al_iu, const float* __restrict__ ar_iu,
    unsigned short* __restrict__ g_u)
{
    int v = blockIdx.x * 4 + (threadIdx.x >> 6);
    if (v >= N_USER) return;
    int lane = threadIdx.x & 63;

    unsigned int hv = *(const unsigned int*)(h_u + (size_t)v * HID + lane * 2);

    int d_uu = cnt[v];
    int d_iu = cnt[N_USER + v];

    const int4* b0 = (const int4*)(bkt + (size_t)v * CAP);
    const int4* b1 = (const int4*)(bkt + (size_t)N_USER * CAP + (size_t)v * CAP);
    int4 q0a = b0[0], q0b = b0[1];
    int4 q1a = b1[0], q1b = b1[1];
    int idx0[8] = {q0a.x, q0a.y, q0a.z, q0a.w, q0b.x, q0b.y, q0b.z, q0b.w};
    int idx1[8] = {q1a.x, q1a.y, q1a.z, q1a.w, q1b.x, q1b.y, q1b.z, q1b.w};

    float s0u = 0.f, s1u = 0.f, s0i = 0.f, s1i = 0.f;
    unsigned int ru[8], ri[8];
    #pragma unroll
    for (int j = 0; j < 8; ++j) {
        int s = j < d_uu ? idx0[j] : v;
        ru[j] = *(const unsigned int*)(h_u + (size_t)s * HID + lane * 2);
    }
    #pragma unroll
    for (int j = 0; j < 8; ++j) {
        int s = j < d_iu ? idx1[j] : v;
        ri[j] = *(const unsigned int*)(h_i + (size_t)s * HID + lane * 2);
    }
    #pragma unroll
    for (int j = 0; j < 8; ++j) {
        float mu = j < d_uu ? 1.f : 0.f;
        float mi = j < d_iu ? 1.f : 0.f;
        s0u += mu * bf2f((unsigned short)ru[j]);
        s1u += mu * bf2f((unsigned short)(ru[j] >> 16));
        s0i += mi * bf2f((unsigned short)ri[j]);
        s1i += mi * bf2f((unsigned short)(ri[j] >> 16));
    }
    if (d_uu > 8) {
        int n = min(d_uu, CAP);
        const int* bq = bkt + (size_t)v * CAP;
        for (int j = 8; j < n; ++j) {
            unsigned int u = *(const unsigned int*)(h_u + (size_t)bq[j] * HID + lane * 2);
            s0u += bf2f((unsigned short)u);
            s1u += bf2f((unsigned short)(u >> 16));
        }
    }
    if (d_iu > 8) {
        int n = min(d_iu, CAP);
        const int* bq = bkt + (size_t)N_USER * CAP + (size_t)v * CAP;
        for (int j = 8; j < n; ++j) {
            unsigned int u = *(const unsigned int*)(h_i + (size_t)bq[j] * HID + lane * 2);
            s0i += bf2f((unsigned short)u);
            s1i += bf2f((unsigned short)(u >> 16));
        }
    }

    float rscale = ar_uu[0] * (float)d_uu + ar_iu[0] * (float)d_iu;
    float acc0 = al_uu[0] * s0u + al_iu[0] * s0i + rscale * bf2f((unsigned short)hv);
    float acc1 = al_uu[0] * s1u + al_iu[0] * s1i + rscale * bf2f((unsigned short)(hv >> 16));

    *(unsigned int*)(g_u + (size_t)v * HID + lane * 2) = cvt_pk_bf16(elu_f(acc0), elu_f(acc1));
}

// item gather: one wave per dst item v; writes final f32 out_i row (ELU applied)
__global__ __launch_bounds__(256) void gather_item_kernel(
    const unsigned short* __restrict__ h_u, const unsigned short* __restrict__ h_i,
    const int* __restrict__ cnt, const int* __restrict__ bkt,
    const float* __restrict__ al_ui, const float* __restrict__ ar_ui,
    float* __restrict__ out_i)
{
    int v = blockIdx.x * 4 + (threadIdx.x >> 6);
    if (v >= N_ITEM) return;
    int lane = threadIdx.x & 63;

    unsigned int hv = *(const unsigned int*)(h_i + (size_t)v * HID + lane * 2);

    int d = cnt[2 * N_USER + v];
    const int4* bq4 = (const int4*)(bkt + 2 * (size_t)N_USER * CAP + (size_t)v * CAP);
    int4 qa = bq4[0], qb = bq4[1];
    int idx[8] = {qa.x, qa.y, qa.z, qa.w, qb.x, qb.y, qb.z, qb.w};

    unsigned int rr[8];
    #pragma unroll
    for (int j = 0; j < 8; ++j) {
        int s = j < d ? idx[j] : v;
        rr[j] = *(const unsigned int*)(h_u + (size_t)s * HID + lane * 2);
    }
    float s0 = 0.f, s1 = 0.f;
    #pragma unroll
    for (int j = 0; j < 8; ++j) {
        float m = j < d ? 1.f : 0.f;
        s0 += m * bf2f((unsigned short)rr[j]);
        s1 += m * bf2f((unsigned short)(rr[j] >> 16));
    }
    if (d > 8) {
        int n = min(d, CAP);
        const int* bq = bkt + 2 * (size_t)N_USER * CAP + (size_t)v * CAP;
        for (int j = 8; j < n; ++j) {
            unsigned int u = *(const unsigned int*)(h_u + (size_t)bq[j] * HID + lane * 2);
            s0 += bf2f((unsigned short)u);
            s1 += bf2f((unsigned short)(u >> 16));
        }
    }

    float rscale = ar_ui[0] * (float)d;
    float2 o;
    o.x = elu_f(rscale * bf2f((unsigned short)hv) + al_ui[0] * s0);
    o.y = elu_f(rscale * bf2f((unsigned short)(hv >> 16)) + al_ui[0] * s1);
    *(float2*)(out_i + (size_t)v * HID + lane * 2) = o;
}

// out_u = g_u @ W_out + b_out ; B-frags from packed Wok (coalesced, L2-resident)
__global__ __launch_bounds__(256) void out_user_kernel(
    const unsigned short* __restrict__ g_u, const unsigned short* __restrict__ Wok,
    const float* __restrict__ bo, float* __restrict__ out, int M)
{
    int wid  = threadIdx.x >> 6;
    int lane = threadIdx.x & 63;
    int row0 = (blockIdx.x * 4 + wid) * 16;
    if (row0 >= M) return;

    int r  = lane & 15;
    int kg = lane >> 4;

    bf16x8 a[4];
    const unsigned short* grow = g_u + (size_t)(row0 + r) * HID;
    #pragma unroll
    for (int kb = 0; kb < 4; ++kb)
        a[kb] = *(const bf16x8*)(grow + kb * 32 + kg * 8);

    const bf16x8* wf = (const bf16x8*)Wok + lane;  // frag stride 64
    #pragma unroll
    for (int nt = 0; nt < 4; ++nt) {
        f32x4 c = {0.f, 0.f, 0.f, 0.f};
        #pragma unroll
        for (int kb = 0; kb < 4; ++kb) {
            bf16x8 bf = wf[(nt * 4 + kb) * 64];
            c = __builtin_amdgcn_mfma_f32_16x16x32_bf16(a[kb], bf, c, 0, 0, 0);
        }
        float bias = bo[nt * 16 + r];
        #pragma unroll
        for (int i = 0; i < 4; ++i)
            out[(size_t)(row0 + kg * 4 + i) * OUT_DIM + nt * 16 + r] = c[i] + bias;
    }
}

extern "C" void kernel_launch(void* const* d_in, const int* in_sizes, int n_in,
                              void* d_out, int out_size, void* d_ws, size_t ws_size,
                              hipStream_t stream)
{
    const float* x_user = (const float*)d_in[0];
    const float* x_item = (const float*)d_in[1];
    const float* W_proj = (const float*)d_in[2];
    const float* b_proj = (const float*)d_in[3];
    const float* al_uu  = (const float*)d_in[4];
    const float* ar_uu  = (const float*)d_in[5];
    const float* al_iu  = (const float*)d_in[6];
    const float* ar_iu  = (const float*)d_in[7];
    const float* al_ui  = (const float*)d_in[8];
    const float* ar_ui  = (const float*)d_in[9];
    const float* W_out  = (const float*)d_in[10];
    const float* b_out  = (const float*)d_in[11];
    const int* edges_uu = (const int*)d_in[12];
    const int* edges_iu = (const int*)d_in[13];
    const int* edges_ui = (const int*)d_in[14];

    char* ws = (char*)d_ws;
    unsigned short* h_u = (unsigned short*)(ws);                   // 12,800,000
    unsigned short* h_i = (unsigned short*)(ws + 12800000);        // 12,800,000
    unsigned short* g_u = (unsigned short*)(ws + 25600000);        // 12,800,000
    unsigned short* Wpk = (unsigned short*)(ws + 38400000);        //     65,536
    unsigned short* Wok = (unsigned short*)(ws + 38465536);        //     16,384
    int* cnt            = (int*)(ws + 38481920);                   //    600,000 (3 x 50000)
    int* bkt            = (int*)(ws + 39081920);                   // 19,200,000 (3 x 50000 x 32)

    float* out_u = (float*)d_out;
    float* out_i = out_u + (size_t)N_USER * OUT_DIM;

    hipMemsetAsync(cnt, 0, 3 * N_USER * sizeof(int), stream);

    dim3 blk(256);
    pack_w_kernel<<<dim3(20), blk, 0, stream>>>(W_proj, W_out, Wpk, Wok);

    proj_kernel<<<dim3(1563), blk, 0, stream>>>(x_user, x_item, Wpk, b_proj, h_u, h_i);

    fill_kernel<<<dim3(782, 3), blk, 0, stream>>>(edges_uu, edges_iu, edges_ui, cnt, bkt);

    gather_user_kernel<<<dim3(12500), blk, 0, stream>>>(h_u, h_i, cnt, bkt,
                                                        al_uu, ar_uu, al_iu, ar_iu, g_u);
    gather_item_kernel<<<dim3(12500), blk, 0, stream>>>(h_u, h_i, cnt, bkt,
                                                        al_ui, ar_ui, out_i);

    out_user_kernel<<<dim3(782), blk, 0, stream>>>(g_u, Wok, b_out, out_u, N_USER);
}

// Round 8
// 119.724 us; speedup vs baseline: 1.0979x; 1.0828x over previous
//
#include <hip/hip_runtime.h>
#include <hip/hip_bf16.h>

typedef short bf16x8 __attribute__((ext_vector_type(8)));
typedef float f32x4 __attribute__((ext_vector_type(4)));

#define N_USER 50000
#define N_ITEM 50000
#define IN_DIM 256
#define HID 128
#define OUT_DIM 64
#define NEDGE 200000
#define CAP 32
#define NSTRIP 3125   // 50000/16

__device__ __forceinline__ float bf2f(unsigned short u) {
    union { unsigned int i; float f; } v; v.i = ((unsigned int)u) << 16; return v.f;
}
__device__ __forceinline__ unsigned short f2bf(float f) {
    union { float f; unsigned int i; } v; v.f = f;
    return (unsigned short)((v.i + 0x7fffu + ((v.i >> 16) & 1u)) >> 16);
}
__device__ __forceinline__ unsigned int cvt_pk_bf16(float a, float b) {
    unsigned int r;
    asm("v_cvt_pk_bf16_f32 %0, %1, %2" : "=v"(r) : "v"(a), "v"(b));
    return r;
}
__device__ __forceinline__ float elu_f(float x) {
    return x > 0.f ? x : (__expf(x) - 1.f);
}

// ---- pack weights into MFMA B-fragment order (bf16), once per launch ----
// Wpk[((nt*8+kb)*64+lane)*8 + j] = bf16(W_proj[(kb*32+kg*8+j)][nt*16+r]), lane=kg*16+r
// Wok[((nt*4+kb)*64+lane)*8 + j] = bf16(W_out [(kb*32+kg*8+j)][nt*16+r])
__global__ __launch_bounds__(256) void pack_w_kernel(
    const float* __restrict__ Wp, const float* __restrict__ Wo,
    unsigned short* __restrict__ Wpk, unsigned short* __restrict__ Wok)
{
    int t = blockIdx.x * 256 + threadIdx.x;
    if (t < 4096) {
        int lane = t & 63, kb = (t >> 6) & 7, nt = t >> 9;
        int r = lane & 15, kg = lane >> 4;
        unsigned short o[8];
        #pragma unroll
        for (int j = 0; j < 8; ++j)
            o[j] = f2bf(Wp[(size_t)(kb * 32 + kg * 8 + j) * HID + nt * 16 + r]);
        #pragma unroll
        for (int j = 0; j < 8; ++j) Wpk[t * 8 + j] = o[j];
    } else if (t < 4096 + 1024) {
        int q = t - 4096;
        int lane = q & 63, kb = (q >> 6) & 3, nt = q >> 8;
        int r = lane & 15, kg = lane >> 4;
        unsigned short o[8];
        #pragma unroll
        for (int j = 0; j < 8; ++j)
            o[j] = f2bf(Wo[(size_t)(kb * 32 + kg * 8 + j) * OUT_DIM + nt * 16 + r]);
        #pragma unroll
        for (int j = 0; j < 8; ++j) Wok[q * 8 + j] = o[j];
    }
}

// Fused projection. Packed W staged into LDS once per 1024-thread block (16 waves,
// 256 rows) -> W global traffic 25MB total instead of 64KB*6252 waves = 400MB.
// LDS layout = packed fragment order, so B-reads are ds_read_b128 at base+lane*16
// (canonical conflict-free pattern). One wave per 16-row strip.
__global__ __launch_bounds__(1024, 4) void proj_kernel(
    const float* __restrict__ x_u, const float* __restrict__ x_i,
    const unsigned short* __restrict__ Wpk, const float* __restrict__ b,
    unsigned short* __restrict__ h_u, unsigned short* __restrict__ h_i)
{
    __shared__ unsigned short lds[HID * IN_DIM];  // 65536 B, packed frag order

    int tid = threadIdx.x;
    #pragma unroll
    for (int it = 0; it < 4; ++it)
        ((int4*)lds)[it * 1024 + tid] = ((const int4*)Wpk)[it * 1024 + tid];
    __syncthreads();

    int wave = tid >> 6;
    int lane = tid & 63;
    int strip = blockIdx.x * 16 + wave;
    strip = min(strip, 2 * NSTRIP - 1);   // clamp: duplicate writes are identical
    const float* x = x_u;
    unsigned short* h = h_u;
    if (strip >= NSTRIP) { strip -= NSTRIP; x = x_i; h = h_i; }

    int row0 = strip * 16;
    int r  = lane & 15;
    int kg = lane >> 4;

    // A frags: x[row0+r][kb*32+kg*8 ..], f32->bf16 via packed cvt
    bf16x8 a[8];
    const float* xrow = x + (size_t)(row0 + r) * IN_DIM;
    #pragma unroll
    for (int kb = 0; kb < 8; ++kb) {
        float4 v0 = *(const float4*)(xrow + kb * 32 + kg * 8);
        float4 v1 = *(const float4*)(xrow + kb * 32 + kg * 8 + 4);
        unsigned int* au = (unsigned int*)&a[kb];
        au[0] = cvt_pk_bf16(v0.x, v0.y);
        au[1] = cvt_pk_bf16(v0.z, v0.w);
        au[2] = cvt_pk_bf16(v1.x, v1.y);
        au[3] = cvt_pk_bf16(v1.z, v1.w);
    }

    const bf16x8* wl = (const bf16x8*)lds + lane;  // frag stride 64
    #pragma unroll
    for (int nt = 0; nt < 8; ++nt) {
        f32x4 c = {0.f, 0.f, 0.f, 0.f};
        #pragma unroll
        for (int kb = 0; kb < 8; ++kb) {
            bf16x8 bf = wl[(nt * 8 + kb) * 64];
            c = __builtin_amdgcn_mfma_f32_16x16x32_bf16(a[kb], bf, c, 0, 0, 0);
        }
        float bias = b[nt * 16 + r];
        #pragma unroll
        for (int i = 0; i < 4; ++i) {
            int rr = row0 + kg * 4 + i;  // C/D: row=(lane>>4)*4+reg, col=lane&15
            h[(size_t)rr * HID + nt * 16 + r] = f2bf(c[i] + bias);
        }
    }
}

// bucket fill: one thread per edge; slot = atomicAdd(cnt[dst]); bucket[dst*CAP+slot]=src
__global__ __launch_bounds__(256) void fill_kernel(
    const int* __restrict__ e_uu, const int* __restrict__ e_iu, const int* __restrict__ e_ui,
    int* __restrict__ cnt, int* __restrict__ bkt)
{
    int rel = blockIdx.y;
    const int* e = rel == 0 ? e_uu : (rel == 1 ? e_iu : e_ui);
    int g = blockIdx.x * 256 + threadIdx.x;
    if (g >= NEDGE) return;
    int2 sd = *(const int2*)(e + 2 * (size_t)g);
    int* c = cnt + (size_t)rel * N_USER;
    int* bk = bkt + (size_t)rel * N_USER * CAP;
    int slot = atomicAdd(&c[sd.y], 1);
    if (slot < CAP) bk[(size_t)sd.y * CAP + slot] = sd.x;
}

// user gather: one wave per dst user v; 8 predicated independent row loads per relation
__global__ __launch_bounds__(256) void gather_user_kernel(
    const unsigned short* __restrict__ h_u, const unsigned short* __restrict__ h_i,
    const int* __restrict__ cnt, const int* __restrict__ bkt,
    const float* __restrict__ al_uu, const float* __restrict__ ar_uu,
    const float* __restrict__ al_iu, const float* __restrict__ ar_iu,
    unsigned short* __restrict__ g_u)
{
    int v = blockIdx.x * 4 + (threadIdx.x >> 6);
    if (v >= N_USER) return;
    int lane = threadIdx.x & 63;

    unsigned int hv = *(const unsigned int*)(h_u + (size_t)v * HID + lane * 2);

    int d_uu = cnt[v];
    int d_iu = cnt[N_USER + v];

    const int4* b0 = (const int4*)(bkt + (size_t)v * CAP);
    const int4* b1 = (const int4*)(bkt + (size_t)N_USER * CAP + (size_t)v * CAP);
    int4 q0a = b0[0], q0b = b0[1];
    int4 q1a = b1[0], q1b = b1[1];
    int idx0[8] = {q0a.x, q0a.y, q0a.z, q0a.w, q0b.x, q0b.y, q0b.z, q0b.w};
    int idx1[8] = {q1a.x, q1a.y, q1a.z, q1a.w, q1b.x, q1b.y, q1b.z, q1b.w};

    float s0u = 0.f, s1u = 0.f, s0i = 0.f, s1i = 0.f;
    unsigned int ru[8], ri[8];
    #pragma unroll
    for (int j = 0; j < 8; ++j) {
        int s = j < d_uu ? idx0[j] : v;
        ru[j] = *(const unsigned int*)(h_u + (size_t)s * HID + lane * 2);
    }
    #pragma unroll
    for (int j = 0; j < 8; ++j) {
        int s = j < d_iu ? idx1[j] : v;
        ri[j] = *(const unsigned int*)(h_i + (size_t)s * HID + lane * 2);
    }
    #pragma unroll
    for (int j = 0; j < 8; ++j) {
        float mu = j < d_uu ? 1.f : 0.f;
        float mi = j < d_iu ? 1.f : 0.f;
        s0u += mu * bf2f((unsigned short)ru[j]);
        s1u += mu * bf2f((unsigned short)(ru[j] >> 16));
        s0i += mi * bf2f((unsigned short)ri[j]);
        s1i += mi * bf2f((unsigned short)(ri[j] >> 16));
    }
    if (d_uu > 8) {
        int n = min(d_uu, CAP);
        const int* bq = bkt + (size_t)v * CAP;
        for (int j = 8; j < n; ++j) {
            unsigned int u = *(const unsigned int*)(h_u + (size_t)bq[j] * HID + lane * 2);
            s0u += bf2f((unsigned short)u);
            s1u += bf2f((unsigned short)(u >> 16));
        }
    }
    if (d_iu > 8) {
        int n = min(d_iu, CAP);
        const int* bq = bkt + (size_t)N_USER * CAP + (size_t)v * CAP;
        for (int j = 8; j < n; ++j) {
            unsigned int u = *(const unsigned int*)(h_i + (size_t)bq[j] * HID + lane * 2);
            s0i += bf2f((unsigned short)u);
            s1i += bf2f((unsigned short)(u >> 16));
        }
    }

    float rscale = ar_uu[0] * (float)d_uu + ar_iu[0] * (float)d_iu;
    float acc0 = al_uu[0] * s0u + al_iu[0] * s0i + rscale * bf2f((unsigned short)hv);
    float acc1 = al_uu[0] * s1u + al_iu[0] * s1i + rscale * bf2f((unsigned short)(hv >> 16));

    *(unsigned int*)(g_u + (size_t)v * HID + lane * 2) = cvt_pk_bf16(elu_f(acc0), elu_f(acc1));
}

// item gather: one wave per dst item v; writes final f32 out_i row (ELU applied)
__global__ __launch_bounds__(256) void gather_item_kernel(
    const unsigned short* __restrict__ h_u, const unsigned short* __restrict__ h_i,
    const int* __restrict__ cnt, const int* __restrict__ bkt,
    const float* __restrict__ al_ui, const float* __restrict__ ar_ui,
    float* __restrict__ out_i)
{
    int v = blockIdx.x * 4 + (threadIdx.x >> 6);
    if (v >= N_ITEM) return;
    int lane = threadIdx.x & 63;

    unsigned int hv = *(const unsigned int*)(h_i + (size_t)v * HID + lane * 2);

    int d = cnt[2 * N_USER + v];
    const int4* bq4 = (const int4*)(bkt + 2 * (size_t)N_USER * CAP + (size_t)v * CAP);
    int4 qa = bq4[0], qb = bq4[1];
    int idx[8] = {qa.x, qa.y, qa.z, qa.w, qb.x, qb.y, qb.z, qb.w};

    unsigned int rr[8];
    #pragma unroll
    for (int j = 0; j < 8; ++j) {
        int s = j < d ? idx[j] : v;
        rr[j] = *(const unsigned int*)(h_u + (size_t)s * HID + lane * 2);
    }
    float s0 = 0.f, s1 = 0.f;
    #pragma unroll
    for (int j = 0; j < 8; ++j) {
        float m = j < d ? 1.f : 0.f;
        s0 += m * bf2f((unsigned short)rr[j]);
        s1 += m * bf2f((unsigned short)(rr[j] >> 16));
    }
    if (d > 8) {
        int n = min(d, CAP);
        const int* bq = bkt + 2 * (size_t)N_USER * CAP + (size_t)v * CAP;
        for (int j = 8; j < n; ++j) {
            unsigned int u = *(const unsigned int*)(h_u + (size_t)bq[j] * HID + lane * 2);
            s0 += bf2f((unsigned short)u);
            s1 += bf2f((unsigned short)(u >> 16));
        }
    }

    float rscale = ar_ui[0] * (float)d;
    float2 o;
    o.x = elu_f(rscale * bf2f((unsigned short)hv) + al_ui[0] * s0);
    o.y = elu_f(rscale * bf2f((unsigned short)(hv >> 16)) + al_ui[0] * s1);
    *(float2*)(out_i + (size_t)v * HID + lane * 2) = o;
}

// out_u = g_u @ W_out + b_out ; B-frags from packed Wok (coalesced, L2-resident)
__global__ __launch_bounds__(256) void out_user_kernel(
    const unsigned short* __restrict__ g_u, const unsigned short* __restrict__ Wok,
    const float* __restrict__ bo, float* __restrict__ out, int M)
{
    int wid  = threadIdx.x >> 6;
    int lane = threadIdx.x & 63;
    int row0 = (blockIdx.x * 4 + wid) * 16;
    if (row0 >= M) return;

    int r  = lane & 15;
    int kg = lane >> 4;

    bf16x8 a[4];
    const unsigned short* grow = g_u + (size_t)(row0 + r) * HID;
    #pragma unroll
    for (int kb = 0; kb < 4; ++kb)
        a[kb] = *(const bf16x8*)(grow + kb * 32 + kg * 8);

    const bf16x8* wf = (const bf16x8*)Wok + lane;  // frag stride 64
    #pragma unroll
    for (int nt = 0; nt < 4; ++nt) {
        f32x4 c = {0.f, 0.f, 0.f, 0.f};
        #pragma unroll
        for (int kb = 0; kb < 4; ++kb) {
            bf16x8 bf = wf[(nt * 4 + kb) * 64];
            c = __builtin_amdgcn_mfma_f32_16x16x32_bf16(a[kb], bf, c, 0, 0, 0);
        }
        float bias = bo[nt * 16 + r];
        #pragma unroll
        for (int i = 0; i < 4; ++i)
            out[(size_t)(row0 + kg * 4 + i) * OUT_DIM + nt * 16 + r] = c[i] + bias;
    }
}

extern "C" void kernel_launch(void* const* d_in, const int* in_sizes, int n_in,
                              void* d_out, int out_size, void* d_ws, size_t ws_size,
                              hipStream_t stream)
{
    const float* x_user = (const float*)d_in[0];
    const float* x_item = (const float*)d_in[1];
    const float* W_proj = (const float*)d_in[2];
    const float* b_proj = (const float*)d_in[3];
    const float* al_uu  = (const float*)d_in[4];
    const float* ar_uu  = (const float*)d_in[5];
    const float* al_iu  = (const float*)d_in[6];
    const float* ar_iu  = (const float*)d_in[7];
    const float* al_ui  = (const float*)d_in[8];
    const float* ar_ui  = (const float*)d_in[9];
    const float* W_out  = (const float*)d_in[10];
    const float* b_out  = (const float*)d_in[11];
    const int* edges_uu = (const int*)d_in[12];
    const int* edges_iu = (const int*)d_in[13];
    const int* edges_ui = (const int*)d_in[14];

    char* ws = (char*)d_ws;
    unsigned short* h_u = (unsigned short*)(ws);                   // 12,800,000
    unsigned short* h_i = (unsigned short*)(ws + 12800000);        // 12,800,000
    unsigned short* g_u = (unsigned short*)(ws + 25600000);        // 12,800,000
    unsigned short* Wpk = (unsigned short*)(ws + 38400000);        //     65,536
    unsigned short* Wok = (unsigned short*)(ws + 38465536);        //     16,384
    int* cnt            = (int*)(ws + 38481920);                   //    600,000 (3 x 50000)
    int* bkt            = (int*)(ws + 39081920);                   // 19,200,000 (3 x 50000 x 32)

    float* out_u = (float*)d_out;
    float* out_i = out_u + (size_t)N_USER * OUT_DIM;

    hipMemsetAsync(cnt, 0, 3 * N_USER * sizeof(int), stream);

    dim3 blk(256);
    pack_w_kernel<<<dim3(20), blk, 0, stream>>>(W_proj, W_out, Wpk, Wok);

    proj_kernel<<<dim3(391), dim3(1024), 0, stream>>>(x_user, x_item, Wpk, b_proj, h_u, h_i);

    fill_kernel<<<dim3(782, 3), blk, 0, stream>>>(edges_uu, edges_iu, edges_ui, cnt, bkt);

    gather_user_kernel<<<dim3(12500), blk, 0, stream>>>(h_u, h_i, cnt, bkt,
                                                        al_uu, ar_uu, al_iu, ar_iu, g_u);
    gather_item_kernel<<<dim3(12500), blk, 0, stream>>>(h_u, h_i, cnt, bkt,
                                                        al_ui, ar_ui, out_i);

    out_user_kernel<<<dim3(782), blk, 0, stream>>>(g_u, Wok, b_out, out_u, N_USER);
}

// Round 9
// 119.689 us; speedup vs baseline: 1.0982x; 1.0003x over previous
//
#include <hip/hip_runtime.h>
#include <hip/hip_bf16.h>

typedef short bf16x8 __attribute__((ext_vector_type(8)));
typedef float f32x4 __attribute__((ext_vector_type(4)));

#define N_USER 50000
#define N_ITEM 50000
#define IN_DIM 256
#define HID 128
#define OUT_DIM 64
#define NEDGE 200000
#define CAP 32
#define NSTRIP 3125   // 50000/16

__device__ __forceinline__ float bf2f(unsigned short u) {
    union { unsigned int i; float f; } v; v.i = ((unsigned int)u) << 16; return v.f;
}
__device__ __forceinline__ unsigned short f2bf(float f) {
    union { float f; unsigned int i; } v; v.f = f;
    return (unsigned short)((v.i + 0x7fffu + ((v.i >> 16) & 1u)) >> 16);
}
__device__ __forceinline__ unsigned int cvt_pk_bf16(float a, float b) {
    unsigned int r;
    asm("v_cvt_pk_bf16_f32 %0, %1, %2" : "=v"(r) : "v"(a), "v"(b));
    return r;
}
__device__ __forceinline__ float elu_f(float x) {
    return x > 0.f ? x : (__expf(x) - 1.f);
}

// ---- pack weights into MFMA fragment order (bf16), once per launch ----
// Wpk (8 replicated copies, one per XCD's L2): B-frags for proj.
//   Wpk[cp*32768 + ((nt*8+kb)*64+lane)*8 + j] = bf16(Wp[(kb*32+kg*8+j)][nt*16+r])
// Wok: B-frags for out_user, k-order matched to the P-permuted g_u layout:
//   k(kb,kg,j) = 16j + 4kb + kg  (bijection onto 0..127)
__global__ __launch_bounds__(256) void pack_w_kernel(
    const float* __restrict__ Wp, const float* __restrict__ Wo,
    unsigned short* __restrict__ Wpk, unsigned short* __restrict__ Wok)
{
    int t = blockIdx.x * 256 + threadIdx.x;
    if (t < 4096) {
        int lane = t & 63, kb = (t >> 6) & 7, nt = t >> 9;
        int r = lane & 15, kg = lane >> 4;
        unsigned short o[8];
        #pragma unroll
        for (int j = 0; j < 8; ++j)
            o[j] = f2bf(Wp[(size_t)(kb * 32 + kg * 8 + j) * HID + nt * 16 + r]);
        for (int cp = 0; cp < 8; ++cp) {
            #pragma unroll
            for (int j = 0; j < 8; ++j) Wpk[cp * 32768 + t * 8 + j] = o[j];
        }
    } else if (t < 4096 + 1024) {
        int q = t - 4096;
        int lane = q & 63, kb = (q >> 6) & 3, nt = q >> 8;
        int r = lane & 15, kg = lane >> 4;
        unsigned short o[8];
        #pragma unroll
        for (int j = 0; j < 8; ++j)
            o[j] = f2bf(Wo[(size_t)(j * 16 + kb * 4 + kg) * OUT_DIM + nt * 16 + r]);
        #pragma unroll
        for (int j = 0; j < 8; ++j) Wok[q * 8 + j] = o[j];
    }
}

// Fused projection. Packed W staged into LDS once per 1024-thread block.
// Stage loads issued FIRST, then x loads + cvt (latency overlap), then ds_write+barrier.
// h is written in P-permuted column order pos = r*8+nt -> one dwordx4 store per row
// per lane (4x256B contiguous segments per instruction).
__global__ __launch_bounds__(1024, 4) void proj_kernel(
    const float* __restrict__ x_u, const float* __restrict__ x_i,
    const unsigned short* __restrict__ Wpk, const float* __restrict__ b,
    unsigned short* __restrict__ h_u, unsigned short* __restrict__ h_i)
{
    __shared__ unsigned short lds[HID * IN_DIM];  // 65536 B, packed frag order

    int tid = threadIdx.x;
    // 1) issue stage loads from this XCD's replica (blockIdx round-robins XCDs)
    const int4* wsel = (const int4*)(Wpk + (size_t)(blockIdx.x & 7) * 32768);
    int4 w0 = wsel[tid];
    int4 w1 = wsel[1024 + tid];
    int4 w2 = wsel[2048 + tid];
    int4 w3 = wsel[3072 + tid];

    int wave = tid >> 6;
    int lane = tid & 63;
    int strip = blockIdx.x * 16 + wave;
    strip = min(strip, 2 * NSTRIP - 1);   // clamp: duplicate writes are identical
    const float* x = x_u;
    unsigned short* h = h_u;
    if (strip >= NSTRIP) { strip -= NSTRIP; x = x_i; h = h_i; }

    int row0 = strip * 16;
    int r  = lane & 15;
    int kg = lane >> 4;

    // 2) x loads + cvt (x-load latency overlaps W-stage latency; cvt's vmcnt wait
    //    drains the older stage loads too, so the ds_writes below are data-ready)
    bf16x8 a[8];
    const float* xrow = x + (size_t)(row0 + r) * IN_DIM;
    #pragma unroll
    for (int kb = 0; kb < 8; ++kb) {
        float4 v0 = *(const float4*)(xrow + kb * 32 + kg * 8);
        float4 v1 = *(const float4*)(xrow + kb * 32 + kg * 8 + 4);
        unsigned int* au = (unsigned int*)&a[kb];
        au[0] = cvt_pk_bf16(v0.x, v0.y);
        au[1] = cvt_pk_bf16(v0.z, v0.w);
        au[2] = cvt_pk_bf16(v1.x, v1.y);
        au[3] = cvt_pk_bf16(v1.z, v1.w);
    }

    // 3) stage into LDS, barrier
    ((int4*)lds)[tid]        = w0;
    ((int4*)lds)[1024 + tid] = w1;
    ((int4*)lds)[2048 + tid] = w2;
    ((int4*)lds)[3072 + tid] = w3;
    __syncthreads();

    float bias[8];
    #pragma unroll
    for (int nt = 0; nt < 8; ++nt) bias[nt] = b[nt * 16 + r];

    f32x4 c[8];
    #pragma unroll
    for (int nt = 0; nt < 8; ++nt) c[nt] = (f32x4){0.f, 0.f, 0.f, 0.f};

    const bf16x8* wl = (const bf16x8*)lds + lane;  // frag stride 64
    #pragma unroll
    for (int nt = 0; nt < 8; ++nt) {
        #pragma unroll
        for (int kb = 0; kb < 8; ++kb)
            c[nt] = __builtin_amdgcn_mfma_f32_16x16x32_bf16(a[kb], wl[(nt * 8 + kb) * 64], c[nt], 0, 0, 0);
    }

    // 4) packed store: row rr, P-positions r*8..r*8+7 (pos = r*8+nt), 16B per lane
    #pragma unroll
    for (int i = 0; i < 4; ++i) {
        uint4 val;
        val.x = cvt_pk_bf16(c[0][i] + bias[0], c[1][i] + bias[1]);
        val.y = cvt_pk_bf16(c[2][i] + bias[2], c[3][i] + bias[3]);
        val.z = cvt_pk_bf16(c[4][i] + bias[4], c[5][i] + bias[5]);
        val.w = cvt_pk_bf16(c[6][i] + bias[6], c[7][i] + bias[7]);
        *(uint4*)(h + (size_t)(row0 + kg * 4 + i) * HID + r * 8) = val;
    }
}

// bucket fill: one thread per edge; slot = atomicAdd(cnt[dst]); bucket[dst*CAP+slot]=src
__global__ __launch_bounds__(256) void fill_kernel(
    const int* __restrict__ e_uu, const int* __restrict__ e_iu, const int* __restrict__ e_ui,
    int* __restrict__ cnt, int* __restrict__ bkt)
{
    int rel = blockIdx.y;
    const int* e = rel == 0 ? e_uu : (rel == 1 ? e_iu : e_ui);
    int g = blockIdx.x * 256 + threadIdx.x;
    if (g >= NEDGE) return;
    int2 sd = *(const int2*)(e + 2 * (size_t)g);
    int* c = cnt + (size_t)rel * N_USER;
    int* bk = bkt + (size_t)rel * N_USER * CAP;
    int slot = atomicAdd(&c[sd.y], 1);
    if (slot < CAP) bk[(size_t)sd.y * CAP + slot] = sd.x;
}

// user gather: one wave per dst user v; elementwise in P-position space (order-agnostic)
__global__ __launch_bounds__(256) void gather_user_kernel(
    const unsigned short* __restrict__ h_u, const unsigned short* __restrict__ h_i,
    const int* __restrict__ cnt, const int* __restrict__ bkt,
    const float* __restrict__ al_uu, const float* __restrict__ ar_uu,
    const float* __restrict__ al_iu, const float* __restrict__ ar_iu,
    unsigned short* __restrict__ g_u)
{
    int v = blockIdx.x * 4 + (threadIdx.x >> 6);
    if (v >= N_USER) return;
    int lane = threadIdx.x & 63;

    unsigned int hv = *(const unsigned int*)(h_u + (size_t)v * HID + lane * 2);

    int d_uu = cnt[v];
    int d_iu = cnt[N_USER + v];

    const int4* b0 = (const int4*)(bkt + (size_t)v * CAP);
    const int4* b1 = (const int4*)(bkt + (size_t)N_USER * CAP + (size_t)v * CAP);
    int4 q0a = b0[0], q0b = b0[1];
    int4 q1a = b1[0], q1b = b1[1];
    int idx0[8] = {q0a.x, q0a.y, q0a.z, q0a.w, q0b.x, q0b.y, q0b.z, q0b.w};
    int idx1[8] = {q1a.x, q1a.y, q1a.z, q1a.w, q1b.x, q1b.y, q1b.z, q1b.w};

    float s0u = 0.f, s1u = 0.f, s0i = 0.f, s1i = 0.f;
    unsigned int ru[8], ri[8];
    #pragma unroll
    for (int j = 0; j < 8; ++j) {
        int s = j < d_uu ? idx0[j] : v;
        ru[j] = *(const unsigned int*)(h_u + (size_t)s * HID + lane * 2);
    }
    #pragma unroll
    for (int j = 0; j < 8; ++j) {
        int s = j < d_iu ? idx1[j] : v;
        ri[j] = *(const unsigned int*)(h_i + (size_t)s * HID + lane * 2);
    }
    #pragma unroll
    for (int j = 0; j < 8; ++j) {
        float mu = j < d_uu ? 1.f : 0.f;
        float mi = j < d_iu ? 1.f : 0.f;
        s0u += mu * bf2f((unsigned short)ru[j]);
        s1u += mu * bf2f((unsigned short)(ru[j] >> 16));
        s0i += mi * bf2f((unsigned short)ri[j]);
        s1i += mi * bf2f((unsigned short)(ri[j] >> 16));
    }
    if (d_uu > 8) {
        int n = min(d_uu, CAP);
        const int* bq = bkt + (size_t)v * CAP;
        for (int j = 8; j < n; ++j) {
            unsigned int u = *(const unsigned int*)(h_u + (size_t)bq[j] * HID + lane * 2);
            s0u += bf2f((unsigned short)u);
            s1u += bf2f((unsigned short)(u >> 16));
        }
    }
    if (d_iu > 8) {
        int n = min(d_iu, CAP);
        const int* bq = bkt + (size_t)N_USER * CAP + (size_t)v * CAP;
        for (int j = 8; j < n; ++j) {
            unsigned int u = *(const unsigned int*)(h_i + (size_t)bq[j] * HID + lane * 2);
            s0i += bf2f((unsigned short)u);
            s1i += bf2f((unsigned short)(u >> 16));
        }
    }

    float rscale = ar_uu[0] * (float)d_uu + ar_iu[0] * (float)d_iu;
    float acc0 = al_uu[0] * s0u + al_iu[0] * s0i + rscale * bf2f((unsigned short)hv);
    float acc1 = al_uu[0] * s1u + al_iu[0] * s1i + rscale * bf2f((unsigned short)(hv >> 16));

    *(unsigned int*)(g_u + (size_t)v * HID + lane * 2) = cvt_pk_bf16(elu_f(acc0), elu_f(acc1));
}

// item gather: reads in P space, writes out_i in CANONICAL col order
// (lane handles positions 2L,2L+1 -> r=L>>2, nt0=(2L)&7 -> cols c0=nt0*16+r, c0+16)
__global__ __launch_bounds__(256) void gather_item_kernel(
    const unsigned short* __restrict__ h_u, const unsigned short* __restrict__ h_i,
    const int* __restrict__ cnt, const int* __restrict__ bkt,
    const float* __restrict__ al_ui, const float* __restrict__ ar_ui,
    float* __restrict__ out_i)
{
    int v = blockIdx.x * 4 + (threadIdx.x >> 6);
    if (v >= N_ITEM) return;
    int lane = threadIdx.x & 63;

    unsigned int hv = *(const unsigned int*)(h_i + (size_t)v * HID + lane * 2);

    int d = cnt[2 * N_USER + v];
    const int4* bq4 = (const int4*)(bkt + 2 * (size_t)N_USER * CAP + (size_t)v * CAP);
    int4 qa = bq4[0], qb = bq4[1];
    int idx[8] = {qa.x, qa.y, qa.z, qa.w, qb.x, qb.y, qb.z, qb.w};

    unsigned int rr[8];
    #pragma unroll
    for (int j = 0; j < 8; ++j) {
        int s = j < d ? idx[j] : v;
        rr[j] = *(const unsigned int*)(h_u + (size_t)s * HID + lane * 2);
    }
    float s0 = 0.f, s1 = 0.f;
    #pragma unroll
    for (int j = 0; j < 8; ++j) {
        float m = j < d ? 1.f : 0.f;
        s0 += m * bf2f((unsigned short)rr[j]);
        s1 += m * bf2f((unsigned short)(rr[j] >> 16));
    }
    if (d > 8) {
        int n = min(d, CAP);
        const int* bq = bkt + 2 * (size_t)N_USER * CAP + (size_t)v * CAP;
        for (int j = 8; j < n; ++j) {
            unsigned int u = *(const unsigned int*)(h_u + (size_t)bq[j] * HID + lane * 2);
            s0 += bf2f((unsigned short)u);
            s1 += bf2f((unsigned short)(u >> 16));
        }
    }

    float rscale = ar_ui[0] * (float)d;
    float o0 = elu_f(rscale * bf2f((unsigned short)hv) + al_ui[0] * s0);
    float o1 = elu_f(rscale * bf2f((unsigned short)(hv >> 16)) + al_ui[0] * s1);

    int r_pos = lane >> 2;
    int c0 = ((2 * lane) & 7) * 16 + r_pos;
    float* orow = out_i + (size_t)v * HID;
    orow[c0]      = o0;
    orow[c0 + 16] = o1;
}

// out_u = g_u @ W_out + b_out ; A-frags read g_u in P space, Wok packed to match
__global__ __launch_bounds__(256) void out_user_kernel(
    const unsigned short* __restrict__ g_u, const unsigned short* __restrict__ Wok,
    const float* __restrict__ bo, float* __restrict__ out, int M)
{
    int wid  = threadIdx.x >> 6;
    int lane = threadIdx.x & 63;
    int row0 = (blockIdx.x * 4 + wid) * 16;
    if (row0 >= M) return;

    int r  = lane & 15;
    int kg = lane >> 4;

    bf16x8 a[4];
    const unsigned short* grow = g_u + (size_t)(row0 + r) * HID;
    #pragma unroll
    for (int kb = 0; kb < 4; ++kb)
        a[kb] = *(const bf16x8*)(grow + kb * 32 + kg * 8);

    const bf16x8* wf = (const bf16x8*)Wok + lane;  // frag stride 64
    #pragma unroll
    for (int nt = 0; nt < 4; ++nt) {
        f32x4 c = {0.f, 0.f, 0.f, 0.f};
        #pragma unroll
        for (int kb = 0; kb < 4; ++kb) {
            bf16x8 bf = wf[(nt * 4 + kb) * 64];
            c = __builtin_amdgcn_mfma_f32_16x16x32_bf16(a[kb], bf, c, 0, 0, 0);
        }
        float bias = bo[nt * 16 + r];
        #pragma unroll
        for (int i = 0; i < 4; ++i)
            out[(size_t)(row0 + kg * 4 + i) * OUT_DIM + nt * 16 + r] = c[i] + bias;
    }
}

extern "C" void kernel_launch(void* const* d_in, const int* in_sizes, int n_in,
                              void* d_out, int out_size, void* d_ws, size_t ws_size,
                              hipStream_t stream)
{
    const float* x_user = (const float*)d_in[0];
    const float* x_item = (const float*)d_in[1];
    const float* W_proj = (const float*)d_in[2];
    const float* b_proj = (const float*)d_in[3];
    const float* al_uu  = (const float*)d_in[4];
    const float* ar_uu  = (const float*)d_in[5];
    const float* al_iu  = (const float*)d_in[6];
    const float* ar_iu  = (const float*)d_in[7];
    const float* al_ui  = (const float*)d_in[8];
    const float* ar_ui  = (const float*)d_in[9];
    const float* W_out  = (const float*)d_in[10];
    const float* b_out  = (const float*)d_in[11];
    const int* edges_uu = (const int*)d_in[12];
    const int* edges_iu = (const int*)d_in[13];
    const int* edges_ui = (const int*)d_in[14];

    char* ws = (char*)d_ws;
    unsigned short* h_u = (unsigned short*)(ws);                   // 12,800,000
    unsigned short* h_i = (unsigned short*)(ws + 12800000);        // 12,800,000
    unsigned short* g_u = (unsigned short*)(ws + 25600000);        // 12,800,000
    unsigned short* Wpk = (unsigned short*)(ws + 38400000);        //    524,288 (8 copies)
    unsigned short* Wok = (unsigned short*)(ws + 38924288);        //     16,384
    int* cnt            = (int*)(ws + 38940672);                   //    600,000 (3 x 50000)
    int* bkt            = (int*)(ws + 39540672);                   // 19,200,000 (3 x 50000 x 32)

    float* out_u = (float*)d_out;
    float* out_i = out_u + (size_t)N_USER * OUT_DIM;

    hipMemsetAsync(cnt, 0, 3 * N_USER * sizeof(int), stream);

    dim3 blk(256);
    pack_w_kernel<<<dim3(20), blk, 0, stream>>>(W_proj, W_out, Wpk, Wok);

    proj_kernel<<<dim3(391), dim3(1024), 0, stream>>>(x_user, x_item, Wpk, b_proj, h_u, h_i);

    fill_kernel<<<dim3(782, 3), blk, 0, stream>>>(edges_uu, edges_iu, edges_ui, cnt, bkt);

    gather_user_kernel<<<dim3(12500), blk, 0, stream>>>(h_u, h_i, cnt, bkt,
                                                        al_uu, ar_uu, al_iu, ar_iu, g_u);
    gather_item_kernel<<<dim3(12500), blk, 0, stream>>>(h_u, h_i, cnt, bkt,
                                                        al_ui, ar_ui, out_i);

    out_user_kernel<<<dim3(782), blk, 0, stream>>>(g_u, Wok, b_out, out_u, N_USER);
}

// Round 10
// 115.234 us; speedup vs baseline: 1.1407x; 1.0387x over previous
//
#include <hip/hip_runtime.h>
#include <hip/hip_bf16.h>

typedef short bf16x8 __attribute__((ext_vector_type(8)));
typedef float f32x4 __attribute__((ext_vector_type(4)));

#define N_USER 50000
#define N_ITEM 50000
#define IN_DIM 256
#define HID 128
#define OUT_DIM 64
#define NEDGE 200000
#define CAP 32
#define NSTRIP 3125   // 50000/16

__device__ __forceinline__ float bf2f(unsigned short u) {
    union { unsigned int i; float f; } v; v.i = ((unsigned int)u) << 16; return v.f;
}
__device__ __forceinline__ unsigned short f2bf(float f) {
    union { float f; unsigned int i; } v; v.f = f;
    return (unsigned short)((v.i + 0x7fffu + ((v.i >> 16) & 1u)) >> 16);
}
__device__ __forceinline__ unsigned int cvt_pk_bf16(float a, float b) {
    unsigned int r;
    asm("v_cvt_pk_bf16_f32 %0, %1, %2" : "=v"(r) : "v"(a), "v"(b));
    return r;
}
__device__ __forceinline__ float elu_f(float x) {
    return x > 0.f ? x : (__expf(x) - 1.f);
}

// ---- pack weights into MFMA fragment order (bf16), once per launch ----
// Wpk (8 replicated copies, one per XCD's L2): B-frags for proj.
// Wok: B-frags for out_user epilogue, k-order matched to the P-permuted h/g layout:
//   k(kb,kg,j) = 16j + 4kb + kg  (bijection onto 0..127)
__global__ __launch_bounds__(256) void pack_w_kernel(
    const float* __restrict__ Wp, const float* __restrict__ Wo,
    unsigned short* __restrict__ Wpk, unsigned short* __restrict__ Wok)
{
    int t = blockIdx.x * 256 + threadIdx.x;
    if (t < 4096) {
        int lane = t & 63, kb = (t >> 6) & 7, nt = t >> 9;
        int r = lane & 15, kg = lane >> 4;
        unsigned short o[8];
        #pragma unroll
        for (int j = 0; j < 8; ++j)
            o[j] = f2bf(Wp[(size_t)(kb * 32 + kg * 8 + j) * HID + nt * 16 + r]);
        for (int cp = 0; cp < 8; ++cp) {
            #pragma unroll
            for (int j = 0; j < 8; ++j) Wpk[cp * 32768 + t * 8 + j] = o[j];
        }
    } else if (t < 4096 + 1024) {
        int q = t - 4096;
        int lane = q & 63, kb = (q >> 6) & 3, nt = q >> 8;
        int r = lane & 15, kg = lane >> 4;
        unsigned short o[8];
        #pragma unroll
        for (int j = 0; j < 8; ++j)
            o[j] = f2bf(Wo[(size_t)(j * 16 + kb * 4 + kg) * OUT_DIM + nt * 16 + r]);
        #pragma unroll
        for (int j = 0; j < 8; ++j) Wok[q * 8 + j] = o[j];
    }
}

// Fused projection (unchanged from round 9).
__global__ __launch_bounds__(1024, 4) void proj_kernel(
    const float* __restrict__ x_u, const float* __restrict__ x_i,
    const unsigned short* __restrict__ Wpk, const float* __restrict__ b,
    unsigned short* __restrict__ h_u, unsigned short* __restrict__ h_i)
{
    __shared__ unsigned short lds[HID * IN_DIM];  // 65536 B, packed frag order

    int tid = threadIdx.x;
    const int4* wsel = (const int4*)(Wpk + (size_t)(blockIdx.x & 7) * 32768);
    int4 w0 = wsel[tid];
    int4 w1 = wsel[1024 + tid];
    int4 w2 = wsel[2048 + tid];
    int4 w3 = wsel[3072 + tid];

    int wave = tid >> 6;
    int lane = tid & 63;
    int strip = blockIdx.x * 16 + wave;
    strip = min(strip, 2 * NSTRIP - 1);
    const float* x = x_u;
    unsigned short* h = h_u;
    if (strip >= NSTRIP) { strip -= NSTRIP; x = x_i; h = h_i; }

    int row0 = strip * 16;
    int r  = lane & 15;
    int kg = lane >> 4;

    bf16x8 a[8];
    const float* xrow = x + (size_t)(row0 + r) * IN_DIM;
    #pragma unroll
    for (int kb = 0; kb < 8; ++kb) {
        float4 v0 = *(const float4*)(xrow + kb * 32 + kg * 8);
        float4 v1 = *(const float4*)(xrow + kb * 32 + kg * 8 + 4);
        unsigned int* au = (unsigned int*)&a[kb];
        au[0] = cvt_pk_bf16(v0.x, v0.y);
        au[1] = cvt_pk_bf16(v0.z, v0.w);
        au[2] = cvt_pk_bf16(v1.x, v1.y);
        au[3] = cvt_pk_bf16(v1.z, v1.w);
    }

    ((int4*)lds)[tid]        = w0;
    ((int4*)lds)[1024 + tid] = w1;
    ((int4*)lds)[2048 + tid] = w2;
    ((int4*)lds)[3072 + tid] = w3;
    __syncthreads();

    float bias[8];
    #pragma unroll
    for (int nt = 0; nt < 8; ++nt) bias[nt] = b[nt * 16 + r];

    f32x4 c[8];
    #pragma unroll
    for (int nt = 0; nt < 8; ++nt) c[nt] = (f32x4){0.f, 0.f, 0.f, 0.f};

    const bf16x8* wl = (const bf16x8*)lds + lane;
    #pragma unroll
    for (int nt = 0; nt < 8; ++nt) {
        #pragma unroll
        for (int kb = 0; kb < 8; ++kb)
            c[nt] = __builtin_amdgcn_mfma_f32_16x16x32_bf16(a[kb], wl[(nt * 8 + kb) * 64], c[nt], 0, 0, 0);
    }

    // packed store: row rr, P-positions pos = r*8+nt (col = nt*16+r), 16B per lane
    #pragma unroll
    for (int i = 0; i < 4; ++i) {
        uint4 val;
        val.x = cvt_pk_bf16(c[0][i] + bias[0], c[1][i] + bias[1]);
        val.y = cvt_pk_bf16(c[2][i] + bias[2], c[3][i] + bias[3]);
        val.z = cvt_pk_bf16(c[4][i] + bias[4], c[5][i] + bias[5]);
        val.w = cvt_pk_bf16(c[6][i] + bias[6], c[7][i] + bias[7]);
        *(uint4*)(h + (size_t)(row0 + kg * 4 + i) * HID + r * 8) = val;
    }
}

// bucket fill: one thread per edge; slot = atomicAdd(cnt[dst]); bucket[dst*CAP+slot]=src
__global__ __launch_bounds__(256) void fill_kernel(
    const int* __restrict__ e_uu, const int* __restrict__ e_iu, const int* __restrict__ e_ui,
    int* __restrict__ cnt, int* __restrict__ bkt)
{
    int rel = blockIdx.y;
    const int* e = rel == 0 ? e_uu : (rel == 1 ? e_iu : e_ui);
    int g = blockIdx.x * 256 + threadIdx.x;
    if (g >= NEDGE) return;
    int2 sd = *(const int2*)(e + 2 * (size_t)g);
    int* c = cnt + (size_t)rel * N_USER;
    int* bk = bkt + (size_t)rel * N_USER * CAP;
    int slot = atomicAdd(&c[sd.y], 1);
    if (slot < CAP) bk[(size_t)sd.y * CAP + slot] = sd.x;
}

// Fused user gather + ELU + output GEMM.
// Block = 256 thr / 4 waves per 16-user strip (grid = 3125, exact).
// Phase 1: wave w gathers rows w*4..w*4+3 (16-deep ILP loads), ELU, writes bf16 row
//          into LDS gbuf with XOR swizzle (row stride 256B is 16-way conflict unswizzled).
//          All threads co-stage Wok (16KB) into LDS.
// Phase 2: wave 0 reads A-frags from gbuf (swizzled, 2-way free) + B-frags from ldsW,
//          16 MFMA, bias, f32 stores. gbuf pos p=kb*32+kg*8+j -> col 16j+4kb+kg = Wok order.
__global__ __launch_bounds__(256, 4) void fused_user_kernel(
    const unsigned short* __restrict__ h_u, const unsigned short* __restrict__ h_i,
    const int* __restrict__ cnt, const int* __restrict__ bkt,
    const float* __restrict__ al_uu, const float* __restrict__ ar_uu,
    const float* __restrict__ al_iu, const float* __restrict__ ar_iu,
    const unsigned short* __restrict__ Wok, const float* __restrict__ bo,
    float* __restrict__ out)
{
    __shared__ unsigned short gbuf[16 * HID];       // 4 KB, swizzled rows
    __shared__ unsigned short ldsW[OUT_DIM * HID];  // 16 KB, frag order

    int tid  = threadIdx.x;
    int wave = tid >> 6;
    int lane = tid & 63;
    int base = blockIdx.x * 16;

    // stage Wok -> LDS: 256 threads x 4 int4 = 16KB
    #pragma unroll
    for (int it = 0; it < 4; ++it)
        ((int4*)ldsW)[it * 256 + tid] = ((const int4*)Wok)[it * 256 + tid];

    float aluu = al_uu[0], aruu = ar_uu[0], aliu = al_iu[0], ariu = ar_iu[0];

    #pragma unroll 1
    for (int q = 0; q < 4; ++q) {
        int vloc = wave * 4 + q;
        int v = base + vloc;

        unsigned int hv = *(const unsigned int*)(h_u + (size_t)v * HID + lane * 2);
        int d_uu = cnt[v];
        int d_iu = cnt[N_USER + v];

        const int4* b0 = (const int4*)(bkt + (size_t)v * CAP);
        const int4* b1 = (const int4*)(bkt + (size_t)N_USER * CAP + (size_t)v * CAP);
        int4 q0a = b0[0], q0b = b0[1];
        int4 q1a = b1[0], q1b = b1[1];
        int idx0[8] = {q0a.x, q0a.y, q0a.z, q0a.w, q0b.x, q0b.y, q0b.z, q0b.w};
        int idx1[8] = {q1a.x, q1a.y, q1a.z, q1a.w, q1b.x, q1b.y, q1b.z, q1b.w};

        unsigned int ru[8], ri[8];
        #pragma unroll
        for (int j = 0; j < 8; ++j) {
            int s = j < d_uu ? idx0[j] : v;
            ru[j] = *(const unsigned int*)(h_u + (size_t)s * HID + lane * 2);
        }
        #pragma unroll
        for (int j = 0; j < 8; ++j) {
            int s = j < d_iu ? idx1[j] : v;
            ri[j] = *(const unsigned int*)(h_i + (size_t)s * HID + lane * 2);
        }
        float s0u = 0.f, s1u = 0.f, s0i = 0.f, s1i = 0.f;
        #pragma unroll
        for (int j = 0; j < 8; ++j) {
            float mu = j < d_uu ? 1.f : 0.f;
            float mi = j < d_iu ? 1.f : 0.f;
            s0u += mu * bf2f((unsigned short)ru[j]);
            s1u += mu * bf2f((unsigned short)(ru[j] >> 16));
            s0i += mi * bf2f((unsigned short)ri[j]);
            s1i += mi * bf2f((unsigned short)(ri[j] >> 16));
        }
        if (d_uu > 8) {
            int n = min(d_uu, CAP);
            const int* bq = bkt + (size_t)v * CAP;
            for (int j = 8; j < n; ++j) {
                unsigned int u = *(const unsigned int*)(h_u + (size_t)bq[j] * HID + lane * 2);
                s0u += bf2f((unsigned short)u);
                s1u += bf2f((unsigned short)(u >> 16));
            }
        }
        if (d_iu > 8) {
            int n = min(d_iu, CAP);
            const int* bq = bkt + (size_t)N_USER * CAP + (size_t)v * CAP;
            for (int j = 8; j < n; ++j) {
                unsigned int u = *(const unsigned int*)(h_i + (size_t)bq[j] * HID + lane * 2);
                s0i += bf2f((unsigned short)u);
                s1i += bf2f((unsigned short)(u >> 16));
            }
        }

        float rscale = aruu * (float)d_uu + ariu * (float)d_iu;
        float acc0 = aluu * s0u + aliu * s0i + rscale * bf2f((unsigned short)hv);
        float acc1 = aluu * s1u + aliu * s1i + rscale * bf2f((unsigned short)(hv >> 16));

        unsigned int packed = cvt_pk_bf16(elu_f(acc0), elu_f(acc1));
        *(unsigned int*)((char*)gbuf + ((vloc * 256 + lane * 4) ^ ((vloc & 7) << 4))) = packed;
    }
    __syncthreads();

    if (wave == 0) {
        int r  = lane & 15;
        int kg = lane >> 4;

        bf16x8 a[4];
        #pragma unroll
        for (int kb = 0; kb < 4; ++kb)
            a[kb] = *(const bf16x8*)((const char*)gbuf +
                      (((r * 256) + kb * 64 + kg * 16) ^ ((r & 7) << 4)));

        const bf16x8* wl = (const bf16x8*)ldsW + lane;
        #pragma unroll
        for (int nt = 0; nt < 4; ++nt) {
            f32x4 c = {0.f, 0.f, 0.f, 0.f};
            #pragma unroll
            for (int kb = 0; kb < 4; ++kb)
                c = __builtin_amdgcn_mfma_f32_16x16x32_bf16(a[kb], wl[(nt * 4 + kb) * 64], c, 0, 0, 0);
            float bias = bo[nt * 16 + r];
            #pragma unroll
            for (int i = 0; i < 4; ++i)
                out[(size_t)(base + kg * 4 + i) * OUT_DIM + nt * 16 + r] = c[i] + bias;
        }
    }
}

// item gather: reads in P space, writes out_i in CANONICAL col order
__global__ __launch_bounds__(256) void gather_item_kernel(
    const unsigned short* __restrict__ h_u, const unsigned short* __restrict__ h_i,
    const int* __restrict__ cnt, const int* __restrict__ bkt,
    const float* __restrict__ al_ui, const float* __restrict__ ar_ui,
    float* __restrict__ out_i)
{
    int v = blockIdx.x * 4 + (threadIdx.x >> 6);
    if (v >= N_ITEM) return;
    int lane = threadIdx.x & 63;

    unsigned int hv = *(const unsigned int*)(h_i + (size_t)v * HID + lane * 2);

    int d = cnt[2 * N_USER + v];
    const int4* bq4 = (const int4*)(bkt + 2 * (size_t)N_USER * CAP + (size_t)v * CAP);
    int4 qa = bq4[0], qb = bq4[1];
    int idx[8] = {qa.x, qa.y, qa.z, qa.w, qb.x, qb.y, qb.z, qb.w};

    unsigned int rr[8];
    #pragma unroll
    for (int j = 0; j < 8; ++j) {
        int s = j < d ? idx[j] : v;
        rr[j] = *(const unsigned int*)(h_u + (size_t)s * HID + lane * 2);
    }
    float s0 = 0.f, s1 = 0.f;
    #pragma unroll
    for (int j = 0; j < 8; ++j) {
        float m = j < d ? 1.f : 0.f;
        s0 += m * bf2f((unsigned short)rr[j]);
        s1 += m * bf2f((unsigned short)(rr[j] >> 16));
    }
    if (d > 8) {
        int n = min(d, CAP);
        const int* bq = bkt + 2 * (size_t)N_USER * CAP + (size_t)v * CAP;
        for (int j = 8; j < n; ++j) {
            unsigned int u = *(const unsigned int*)(h_u + (size_t)bq[j] * HID + lane * 2);
            s0 += bf2f((unsigned short)u);
            s1 += bf2f((unsigned short)(u >> 16));
        }
    }

    float rscale = ar_ui[0] * (float)d;
    float o0 = elu_f(rscale * bf2f((unsigned short)hv) + al_ui[0] * s0);
    float o1 = elu_f(rscale * bf2f((unsigned short)(hv >> 16)) + al_ui[0] * s1);

    int r_pos = lane >> 2;
    int c0 = ((2 * lane) & 7) * 16 + r_pos;
    float* orow = out_i + (size_t)v * HID;
    orow[c0]      = o0;
    orow[c0 + 16] = o1;
}

extern "C" void kernel_launch(void* const* d_in, const int* in_sizes, int n_in,
                              void* d_out, int out_size, void* d_ws, size_t ws_size,
                              hipStream_t stream)
{
    const float* x_user = (const float*)d_in[0];
    const float* x_item = (const float*)d_in[1];
    const float* W_proj = (const float*)d_in[2];
    const float* b_proj = (const float*)d_in[3];
    const float* al_uu  = (const float*)d_in[4];
    const float* ar_uu  = (const float*)d_in[5];
    const float* al_iu  = (const float*)d_in[6];
    const float* ar_iu  = (const float*)d_in[7];
    const float* al_ui  = (const float*)d_in[8];
    const float* ar_ui  = (const float*)d_in[9];
    const float* W_out  = (const float*)d_in[10];
    const float* b_out  = (const float*)d_in[11];
    const int* edges_uu = (const int*)d_in[12];
    const int* edges_iu = (const int*)d_in[13];
    const int* edges_ui = (const int*)d_in[14];

    char* ws = (char*)d_ws;
    unsigned short* h_u = (unsigned short*)(ws);                   // 12,800,000
    unsigned short* h_i = (unsigned short*)(ws + 12800000);        // 12,800,000
    unsigned short* Wpk = (unsigned short*)(ws + 25600000);        //    524,288 (8 copies)
    unsigned short* Wok = (unsigned short*)(ws + 26124288);        //     16,384
    int* cnt            = (int*)(ws + 26140672);                   //    600,000 (3 x 50000)
    int* bkt            = (int*)(ws + 26740672);                   // 19,200,000 (3 x 50000 x 32)

    float* out_u = (float*)d_out;
    float* out_i = out_u + (size_t)N_USER * OUT_DIM;

    hipMemsetAsync(cnt, 0, 3 * N_USER * sizeof(int), stream);

    dim3 blk(256);
    pack_w_kernel<<<dim3(20), blk, 0, stream>>>(W_proj, W_out, Wpk, Wok);

    proj_kernel<<<dim3(391), dim3(1024), 0, stream>>>(x_user, x_item, Wpk, b_proj, h_u, h_i);

    fill_kernel<<<dim3(782, 3), blk, 0, stream>>>(edges_uu, edges_iu, edges_ui, cnt, bkt);

    fused_user_kernel<<<dim3(NSTRIP), blk, 0, stream>>>(h_u, h_i, cnt, bkt,
                                                        al_uu, ar_uu, al_iu, ar_iu,
                                                        Wok, b_out, out_u);
    gather_item_kernel<<<dim3(12500), blk, 0, stream>>>(h_u, h_i, cnt, bkt,
                                                        al_ui, ar_ui, out_i);
}

// Round 11
// 113.965 us; speedup vs baseline: 1.1534x; 1.0111x over previous
//
#include <hip/hip_runtime.h>
#include <hip/hip_bf16.h>

typedef short bf16x8 __attribute__((ext_vector_type(8)));
typedef float f32x4 __attribute__((ext_vector_type(4)));

#define N_USER 50000
#define N_ITEM 50000
#define IN_DIM 256
#define HID 128
#define OUT_DIM 64
#define NEDGE 200000
#define CAP 32
#define NSTRIP 3125   // 50000/16
#define PROJ_GRID 512 // 2 blocks/CU (LDS 64KB); strips taken mod 2*NSTRIP

__device__ __forceinline__ float bf2f(unsigned short u) {
    union { unsigned int i; float f; } v; v.i = ((unsigned int)u) << 16; return v.f;
}
__device__ __forceinline__ unsigned short f2bf(float f) {
    union { float f; unsigned int i; } v; v.f = f;
    return (unsigned short)((v.i + 0x7fffu + ((v.i >> 16) & 1u)) >> 16);
}
__device__ __forceinline__ unsigned int cvt_pk_bf16(float a, float b) {
    unsigned int r;
    asm("v_cvt_pk_bf16_f32 %0, %1, %2" : "=v"(r) : "v"(a), "v"(b));
    return r;
}
__device__ __forceinline__ float elu_f(float x) {
    return x > 0.f ? x : (__expf(x) - 1.f);
}

// ---- pack weights (frag order) + zero cnt, one launch ----
__global__ __launch_bounds__(256) void pack_w_kernel(
    const float* __restrict__ Wp, const float* __restrict__ Wo,
    unsigned short* __restrict__ Wpk, unsigned short* __restrict__ Wok,
    int* __restrict__ cnt)
{
    int bid = blockIdx.x;
    if (bid >= 20) {
        int idx = (bid - 20) * 256 + threadIdx.x;
        if (idx < 3 * N_USER) cnt[idx] = 0;
        return;
    }
    int t = bid * 256 + threadIdx.x;
    if (t < 4096) {
        int lane = t & 63, kb = (t >> 6) & 7, nt = t >> 9;
        int r = lane & 15, kg = lane >> 4;
        unsigned short o[8];
        #pragma unroll
        for (int j = 0; j < 8; ++j)
            o[j] = f2bf(Wp[(size_t)(kb * 32 + kg * 8 + j) * HID + nt * 16 + r]);
        for (int cp = 0; cp < 8; ++cp) {
            #pragma unroll
            for (int j = 0; j < 8; ++j) Wpk[cp * 32768 + t * 8 + j] = o[j];
        }
    } else if (t < 4096 + 1024) {
        int q = t - 4096;
        int lane = q & 63, kb = (q >> 6) & 3, nt = q >> 8;
        int r = lane & 15, kg = lane >> 4;
        unsigned short o[8];
        #pragma unroll
        for (int j = 0; j < 8; ++j)
            o[j] = f2bf(Wo[(size_t)(j * 16 + kb * 4 + kg) * OUT_DIM + nt * 16 + r]);
        #pragma unroll
        for (int j = 0; j < 8; ++j) Wok[q * 8 + j] = o[j];
    }
}

// Fused projection. Grid 512 (2 blocks/CU co-resident; phase-offset pairs overlap
// load and MFMA phases). strip = global_wave % 6250 -> strips 0..1941 duplicated;
// duplicate h writes are byte-identical (benign).
__global__ __launch_bounds__(1024, 4) void proj_kernel(
    const float* __restrict__ x_u, const float* __restrict__ x_i,
    const unsigned short* __restrict__ Wpk, const float* __restrict__ b,
    unsigned short* __restrict__ h_u, unsigned short* __restrict__ h_i)
{
    __shared__ unsigned short lds[HID * IN_DIM];  // 65536 B, packed frag order

    int tid = threadIdx.x;
    const int4* wsel = (const int4*)(Wpk + (size_t)(blockIdx.x & 7) * 32768);
    int4 w0 = wsel[tid];
    int4 w1 = wsel[1024 + tid];
    int4 w2 = wsel[2048 + tid];
    int4 w3 = wsel[3072 + tid];

    int wave = tid >> 6;
    int lane = tid & 63;
    int strip = (blockIdx.x * 16 + wave) % (2 * NSTRIP);
    const float* x = x_u;
    unsigned short* h = h_u;
    if (strip >= NSTRIP) { strip -= NSTRIP; x = x_i; h = h_i; }

    int row0 = strip * 16;
    int r  = lane & 15;
    int kg = lane >> 4;

    bf16x8 a[8];
    const float* xrow = x + (size_t)(row0 + r) * IN_DIM;
    #pragma unroll
    for (int kb = 0; kb < 8; ++kb) {
        float4 v0 = *(const float4*)(xrow + kb * 32 + kg * 8);
        float4 v1 = *(const float4*)(xrow + kb * 32 + kg * 8 + 4);
        unsigned int* au = (unsigned int*)&a[kb];
        au[0] = cvt_pk_bf16(v0.x, v0.y);
        au[1] = cvt_pk_bf16(v0.z, v0.w);
        au[2] = cvt_pk_bf16(v1.x, v1.y);
        au[3] = cvt_pk_bf16(v1.z, v1.w);
    }

    ((int4*)lds)[tid]        = w0;
    ((int4*)lds)[1024 + tid] = w1;
    ((int4*)lds)[2048 + tid] = w2;
    ((int4*)lds)[3072 + tid] = w3;
    __syncthreads();

    float bias[8];
    #pragma unroll
    for (int nt = 0; nt < 8; ++nt) bias[nt] = b[nt * 16 + r];

    f32x4 c[8];
    #pragma unroll
    for (int nt = 0; nt < 8; ++nt) c[nt] = (f32x4){0.f, 0.f, 0.f, 0.f};

    const bf16x8* wl = (const bf16x8*)lds + lane;
    #pragma unroll
    for (int nt = 0; nt < 8; ++nt) {
        #pragma unroll
        for (int kb = 0; kb < 8; ++kb)
            c[nt] = __builtin_amdgcn_mfma_f32_16x16x32_bf16(a[kb], wl[(nt * 8 + kb) * 64], c[nt], 0, 0, 0);
    }

    // packed store: row rr, P-positions pos = r*8+nt (col = nt*16+r), 16B per lane
    #pragma unroll
    for (int i = 0; i < 4; ++i) {
        uint4 val;
        val.x = cvt_pk_bf16(c[0][i] + bias[0], c[1][i] + bias[1]);
        val.y = cvt_pk_bf16(c[2][i] + bias[2], c[3][i] + bias[3]);
        val.z = cvt_pk_bf16(c[4][i] + bias[4], c[5][i] + bias[5]);
        val.w = cvt_pk_bf16(c[6][i] + bias[6], c[7][i] + bias[7]);
        *(uint4*)(h + (size_t)(row0 + kg * 4 + i) * HID + r * 8) = val;
    }
}

// bucket fill: one thread per edge; slot = atomicAdd(cnt[dst]); bucket[dst*CAP+slot]=src
__global__ __launch_bounds__(256) void fill_kernel(
    const int* __restrict__ e_uu, const int* __restrict__ e_iu, const int* __restrict__ e_ui,
    int* __restrict__ cnt, int* __restrict__ bkt)
{
    int rel = blockIdx.y;
    const int* e = rel == 0 ? e_uu : (rel == 1 ? e_iu : e_ui);
    int g = blockIdx.x * 256 + threadIdx.x;
    if (g >= NEDGE) return;
    int2 sd = *(const int2*)(e + 2 * (size_t)g);
    int* c = cnt + (size_t)rel * N_USER;
    int* bk = bkt + (size_t)rel * N_USER * CAP;
    int slot = atomicAdd(&c[sd.y], 1);
    if (slot < CAP) bk[(size_t)sd.y * CAP + slot] = sd.x;
}

// Merged epilogue: blocks [0,3125) = fused user gather+ELU+GEMM; [3125,15625) = item gather.
__global__ __launch_bounds__(256, 4) void epilogue_kernel(
    const unsigned short* __restrict__ h_u, const unsigned short* __restrict__ h_i,
    const int* __restrict__ cnt, const int* __restrict__ bkt,
    const float* __restrict__ al_uu, const float* __restrict__ ar_uu,
    const float* __restrict__ al_iu, const float* __restrict__ ar_iu,
    const float* __restrict__ al_ui, const float* __restrict__ ar_ui,
    const unsigned short* __restrict__ Wok, const float* __restrict__ bo,
    float* __restrict__ out_u, float* __restrict__ out_i)
{
    __shared__ unsigned short gbuf[16 * HID];       // 4 KB (user path)
    __shared__ unsigned short ldsW[OUT_DIM * HID];  // 16 KB (user path)

    int tid  = threadIdx.x;
    int wave = tid >> 6;
    int lane = tid & 63;

    if (blockIdx.x >= NSTRIP) {
        // ---- item gather path ----
        int v = (blockIdx.x - NSTRIP) * 4 + wave;
        if (v >= N_ITEM) return;

        unsigned int hv = *(const unsigned int*)(h_i + (size_t)v * HID + lane * 2);

        int d = cnt[2 * N_USER + v];
        const int4* bq4 = (const int4*)(bkt + 2 * (size_t)N_USER * CAP + (size_t)v * CAP);
        int4 qa = bq4[0], qb = bq4[1];
        int idx[8] = {qa.x, qa.y, qa.z, qa.w, qb.x, qb.y, qb.z, qb.w};

        unsigned int rr[8];
        #pragma unroll
        for (int j = 0; j < 8; ++j) {
            int s = j < d ? idx[j] : v;
            rr[j] = *(const unsigned int*)(h_u + (size_t)s * HID + lane * 2);
        }
        float s0 = 0.f, s1 = 0.f;
        #pragma unroll
        for (int j = 0; j < 8; ++j) {
            float m = j < d ? 1.f : 0.f;
            s0 += m * bf2f((unsigned short)rr[j]);
            s1 += m * bf2f((unsigned short)(rr[j] >> 16));
        }
        if (d > 8) {
            int n = min(d, CAP);
            const int* bq = bkt + 2 * (size_t)N_USER * CAP + (size_t)v * CAP;
            for (int j = 8; j < n; ++j) {
                unsigned int u = *(const unsigned int*)(h_u + (size_t)bq[j] * HID + lane * 2);
                s0 += bf2f((unsigned short)u);
                s1 += bf2f((unsigned short)(u >> 16));
            }
        }

        float rscale = ar_ui[0] * (float)d;
        float o0 = elu_f(rscale * bf2f((unsigned short)hv) + al_ui[0] * s0);
        float o1 = elu_f(rscale * bf2f((unsigned short)(hv >> 16)) + al_ui[0] * s1);

        int r_pos = lane >> 2;
        int c0 = ((2 * lane) & 7) * 16 + r_pos;
        float* orow = out_i + (size_t)v * HID;
        orow[c0]      = o0;
        orow[c0 + 16] = o1;
        return;
    }

    // ---- fused user path ----
    int base = blockIdx.x * 16;

    #pragma unroll
    for (int it = 0; it < 4; ++it)
        ((int4*)ldsW)[it * 256 + tid] = ((const int4*)Wok)[it * 256 + tid];

    float aluu = al_uu[0], aruu = ar_uu[0], aliu = al_iu[0], ariu = ar_iu[0];

    #pragma unroll 1
    for (int q = 0; q < 4; ++q) {
        int vloc = wave * 4 + q;
        int v = base + vloc;

        unsigned int hv = *(const unsigned int*)(h_u + (size_t)v * HID + lane * 2);
        int d_uu = cnt[v];
        int d_iu = cnt[N_USER + v];

        const int4* b0 = (const int4*)(bkt + (size_t)v * CAP);
        const int4* b1 = (const int4*)(bkt + (size_t)N_USER * CAP + (size_t)v * CAP);
        int4 q0a = b0[0], q0b = b0[1];
        int4 q1a = b1[0], q1b = b1[1];
        int idx0[8] = {q0a.x, q0a.y, q0a.z, q0a.w, q0b.x, q0b.y, q0b.z, q0b.w};
        int idx1[8] = {q1a.x, q1a.y, q1a.z, q1a.w, q1b.x, q1b.y, q1b.z, q1b.w};

        unsigned int ru[8], ri[8];
        #pragma unroll
        for (int j = 0; j < 8; ++j) {
            int s = j < d_uu ? idx0[j] : v;
            ru[j] = *(const unsigned int*)(h_u + (size_t)s * HID + lane * 2);
        }
        #pragma unroll
        for (int j = 0; j < 8; ++j) {
            int s = j < d_iu ? idx1[j] : v;
            ri[j] = *(const unsigned int*)(h_i + (size_t)s * HID + lane * 2);
        }
        float s0u = 0.f, s1u = 0.f, s0i = 0.f, s1i = 0.f;
        #pragma unroll
        for (int j = 0; j < 8; ++j) {
            float mu = j < d_uu ? 1.f : 0.f;
            float mi = j < d_iu ? 1.f : 0.f;
            s0u += mu * bf2f((unsigned short)ru[j]);
            s1u += mu * bf2f((unsigned short)(ru[j] >> 16));
            s0i += mi * bf2f((unsigned short)ri[j]);
            s1i += mi * bf2f((unsigned short)(ri[j] >> 16));
        }
        if (d_uu > 8) {
            int n = min(d_uu, CAP);
            const int* bq = bkt + (size_t)v * CAP;
            for (int j = 8; j < n; ++j) {
                unsigned int u = *(const unsigned int*)(h_u + (size_t)bq[j] * HID + lane * 2);
                s0u += bf2f((unsigned short)u);
                s1u += bf2f((unsigned short)(u >> 16));
            }
        }
        if (d_iu > 8) {
            int n = min(d_iu, CAP);
            const int* bq = bkt + (size_t)N_USER * CAP + (size_t)v * CAP;
            for (int j = 8; j < n; ++j) {
                unsigned int u = *(const unsigned int*)(h_i + (size_t)bq[j] * HID + lane * 2);
                s0i += bf2f((unsigned short)u);
                s1i += bf2f((unsigned short)(u >> 16));
            }
        }

        float rscale = aruu * (float)d_uu + ariu * (float)d_iu;
        float acc0 = aluu * s0u + aliu * s0i + rscale * bf2f((unsigned short)hv);
        float acc1 = aluu * s1u + aliu * s1i + rscale * bf2f((unsigned short)(hv >> 16));

        unsigned int packed = cvt_pk_bf16(elu_f(acc0), elu_f(acc1));
        *(unsigned int*)((char*)gbuf + ((vloc * 256 + lane * 4) ^ ((vloc & 7) << 4))) = packed;
    }
    __syncthreads();

    if (wave == 0) {
        int r  = lane & 15;
        int kg = lane >> 4;

        bf16x8 a[4];
        #pragma unroll
        for (int kb = 0; kb < 4; ++kb)
            a[kb] = *(const bf16x8*)((const char*)gbuf +
                      (((r * 256) + kb * 64 + kg * 16) ^ ((r & 7) << 4)));

        const bf16x8* wl = (const bf16x8*)ldsW + lane;
        #pragma unroll
        for (int nt = 0; nt < 4; ++nt) {
            f32x4 c = {0.f, 0.f, 0.f, 0.f};
            #pragma unroll
            for (int kb = 0; kb < 4; ++kb)
                c = __builtin_amdgcn_mfma_f32_16x16x32_bf16(a[kb], wl[(nt * 4 + kb) * 64], c, 0, 0, 0);
            float bias = bo[nt * 16 + r];
            #pragma unroll
            for (int i = 0; i < 4; ++i)
                out_u[(size_t)(base + kg * 4 + i) * OUT_DIM + nt * 16 + r] = c[i] + bias;
        }
    }
}

extern "C" void kernel_launch(void* const* d_in, const int* in_sizes, int n_in,
                              void* d_out, int out_size, void* d_ws, size_t ws_size,
                              hipStream_t stream)
{
    const float* x_user = (const float*)d_in[0];
    const float* x_item = (const float*)d_in[1];
    const float* W_proj = (const float*)d_in[2];
    const float* b_proj = (const float*)d_in[3];
    const float* al_uu  = (const float*)d_in[4];
    const float* ar_uu  = (const float*)d_in[5];
    const float* al_iu  = (const float*)d_in[6];
    const float* ar_iu  = (const float*)d_in[7];
    const float* al_ui  = (const float*)d_in[8];
    const float* ar_ui  = (const float*)d_in[9];
    const float* W_out  = (const float*)d_in[10];
    const float* b_out  = (const float*)d_in[11];
    const int* edges_uu = (const int*)d_in[12];
    const int* edges_iu = (const int*)d_in[13];
    const int* edges_ui = (const int*)d_in[14];

    char* ws = (char*)d_ws;
    unsigned short* h_u = (unsigned short*)(ws);                   // 12,800,000
    unsigned short* h_i = (unsigned short*)(ws + 12800000);        // 12,800,000
    unsigned short* Wpk = (unsigned short*)(ws + 25600000);        //    524,288 (8 copies)
    unsigned short* Wok = (unsigned short*)(ws + 26124288);        //     16,384
    int* cnt            = (int*)(ws + 26140672);                   //    600,000 (3 x 50000)
    int* bkt            = (int*)(ws + 26740672);                   // 19,200,000 (3 x 50000 x 32)

    float* out_u = (float*)d_out;
    float* out_i = out_u + (size_t)N_USER * OUT_DIM;

    dim3 blk(256);
    // pack W (blocks 0..19) + zero cnt (blocks 20..605)
    pack_w_kernel<<<dim3(606), blk, 0, stream>>>(W_proj, W_out, Wpk, Wok, cnt);

    proj_kernel<<<dim3(PROJ_GRID), dim3(1024), 0, stream>>>(x_user, x_item, Wpk, b_proj, h_u, h_i);

    fill_kernel<<<dim3(782, 3), blk, 0, stream>>>(edges_uu, edges_iu, edges_ui, cnt, bkt);

    epilogue_kernel<<<dim3(NSTRIP + 12500), blk, 0, stream>>>(
        h_u, h_i, cnt, bkt, al_uu, ar_uu, al_iu, ar_iu, al_ui, ar_ui,
        Wok, b_out, out_u, out_i);
}

// Round 12
// 97.277 us; speedup vs baseline: 1.3513x; 1.1716x over previous
//
#include <hip/hip_runtime.h>
#include <hip/hip_bf16.h>

typedef short bf16x8 __attribute__((ext_vector_type(8)));
typedef float f32x4 __attribute__((ext_vector_type(4)));

#define N_USER 50000
#define N_ITEM 50000
#define IN_DIM 256
#define HID 128
#define OUT_DIM 64
#define NEDGE 200000
#define CAP 32
#define NSTRIP 3125    // 50000/16
#define PROJ_GRID 391  // ceil(6250 strips / 16 waves)
#define FILL_GRID 588  // ceil(600000 edges / 1024)

__device__ __forceinline__ float bf2f(unsigned short u) {
    union { unsigned int i; float f; } v; v.i = ((unsigned int)u) << 16; return v.f;
}
__device__ __forceinline__ unsigned short f2bf(float f) {
    union { float f; unsigned int i; } v; v.f = f;
    return (unsigned short)((v.i + 0x7fffu + ((v.i >> 16) & 1u)) >> 16);
}
__device__ __forceinline__ unsigned int cvt_pk_bf16(float a, float b) {
    unsigned int r;
    asm("v_cvt_pk_bf16_f32 %0, %1, %2" : "=v"(r) : "v"(a), "v"(b));
    return r;
}
__device__ __forceinline__ float elu_f(float x) {
    return x > 0.f ? x : (__expf(x) - 1.f);
}

// ---- pack weights (frag order) + zero cnt, one launch ----
__global__ __launch_bounds__(256) void pack_w_kernel(
    const float* __restrict__ Wp, const float* __restrict__ Wo,
    unsigned short* __restrict__ Wpk, unsigned short* __restrict__ Wok,
    int* __restrict__ cnt)
{
    int bid = blockIdx.x;
    if (bid >= 20) {
        int idx = (bid - 20) * 256 + threadIdx.x;
        if (idx < 3 * N_USER) cnt[idx] = 0;
        return;
    }
    int t = bid * 256 + threadIdx.x;
    if (t < 4096) {
        int lane = t & 63, kb = (t >> 6) & 7, nt = t >> 9;
        int r = lane & 15, kg = lane >> 4;
        unsigned short o[8];
        #pragma unroll
        for (int j = 0; j < 8; ++j)
            o[j] = f2bf(Wp[(size_t)(kb * 32 + kg * 8 + j) * HID + nt * 16 + r]);
        for (int cp = 0; cp < 8; ++cp) {
            #pragma unroll
            for (int j = 0; j < 8; ++j) Wpk[cp * 32768 + t * 8 + j] = o[j];
        }
    } else if (t < 4096 + 1024) {
        int q = t - 4096;
        int lane = q & 63, kb = (q >> 6) & 3, nt = q >> 8;
        int r = lane & 15, kg = lane >> 4;
        unsigned short o[8];
        #pragma unroll
        for (int j = 0; j < 8; ++j)
            o[j] = f2bf(Wo[(size_t)(j * 16 + kb * 4 + kg) * OUT_DIM + nt * 16 + r]);
        #pragma unroll
        for (int j = 0; j < 8; ++j) Wok[q * 8 + j] = o[j];
    }
}

// Fused projection (blocks [0,391)) + edge bucket-fill (blocks [391,979)).
// Fill blocks ride the proj dispatch's occupancy tail; cnt is zeroed by pack_w
// (prior dispatch), and the epilogue dispatch boundary orders fill before gather.
__global__ __launch_bounds__(1024, 4) void proj_kernel(
    const float* __restrict__ x_u, const float* __restrict__ x_i,
    const unsigned short* __restrict__ Wpk, const float* __restrict__ b,
    unsigned short* __restrict__ h_u, unsigned short* __restrict__ h_i,
    const int* __restrict__ e_uu, const int* __restrict__ e_iu,
    const int* __restrict__ e_ui, int* __restrict__ cnt, int* __restrict__ bkt)
{
    __shared__ unsigned short lds[HID * IN_DIM];  // 65536 B, packed frag order

    int tid = threadIdx.x;
    int bid = blockIdx.x;

    if (bid >= PROJ_GRID) {
        // ---- edge bucket-fill path ----
        int g = (bid - PROJ_GRID) * 1024 + tid;
        if (g >= 3 * NEDGE) return;
        int rel = g >= 2 * NEDGE ? 2 : (g >= NEDGE ? 1 : 0);
        const int* e = rel == 0 ? e_uu : (rel == 1 ? e_iu : e_ui);
        int eid = g - rel * NEDGE;
        int2 sd = *(const int2*)(e + 2 * (size_t)eid);
        int* c  = cnt + (size_t)rel * N_USER;
        int* bk = bkt + (size_t)rel * N_USER * CAP;
        int slot = atomicAdd(&c[sd.y], 1);
        if (slot < CAP) bk[(size_t)sd.y * CAP + slot] = sd.x;
        return;
    }

    // ---- projection path ----
    const int4* wsel = (const int4*)(Wpk + (size_t)(bid & 7) * 32768);
    int4 w0 = wsel[tid];
    int4 w1 = wsel[1024 + tid];
    int4 w2 = wsel[2048 + tid];
    int4 w3 = wsel[3072 + tid];

    int wave = tid >> 6;
    int lane = tid & 63;
    int strip = bid * 16 + wave;
    strip = min(strip, 2 * NSTRIP - 1);   // clamp: duplicate writes are identical
    const float* x = x_u;
    unsigned short* h = h_u;
    if (strip >= NSTRIP) { strip -= NSTRIP; x = x_i; h = h_i; }

    int row0 = strip * 16;
    int r  = lane & 15;
    int kg = lane >> 4;

    bf16x8 a[8];
    const float* xrow = x + (size_t)(row0 + r) * IN_DIM;
    #pragma unroll
    for (int kb = 0; kb < 8; ++kb) {
        float4 v0 = *(const float4*)(xrow + kb * 32 + kg * 8);
        float4 v1 = *(const float4*)(xrow + kb * 32 + kg * 8 + 4);
        unsigned int* au = (unsigned int*)&a[kb];
        au[0] = cvt_pk_bf16(v0.x, v0.y);
        au[1] = cvt_pk_bf16(v0.z, v0.w);
        au[2] = cvt_pk_bf16(v1.x, v1.y);
        au[3] = cvt_pk_bf16(v1.z, v1.w);
    }

    ((int4*)lds)[tid]        = w0;
    ((int4*)lds)[1024 + tid] = w1;
    ((int4*)lds)[2048 + tid] = w2;
    ((int4*)lds)[3072 + tid] = w3;
    __syncthreads();

    float bias[8];
    #pragma unroll
    for (int nt = 0; nt < 8; ++nt) bias[nt] = b[nt * 16 + r];

    f32x4 c[8];
    #pragma unroll
    for (int nt = 0; nt < 8; ++nt) c[nt] = (f32x4){0.f, 0.f, 0.f, 0.f};

    const bf16x8* wl = (const bf16x8*)lds + lane;
    #pragma unroll
    for (int nt = 0; nt < 8; ++nt) {
        #pragma unroll
        for (int kb = 0; kb < 8; ++kb)
            c[nt] = __builtin_amdgcn_mfma_f32_16x16x32_bf16(a[kb], wl[(nt * 8 + kb) * 64], c[nt], 0, 0, 0);
    }

    // packed store: row rr, P-positions pos = r*8+nt (col = nt*16+r), 16B per lane
    #pragma unroll
    for (int i = 0; i < 4; ++i) {
        uint4 val;
        val.x = cvt_pk_bf16(c[0][i] + bias[0], c[1][i] + bias[1]);
        val.y = cvt_pk_bf16(c[2][i] + bias[2], c[3][i] + bias[3]);
        val.z = cvt_pk_bf16(c[4][i] + bias[4], c[5][i] + bias[5]);
        val.w = cvt_pk_bf16(c[6][i] + bias[6], c[7][i] + bias[7]);
        *(uint4*)(h + (size_t)(row0 + kg * 4 + i) * HID + r * 8) = val;
    }
}

// Merged epilogue: blocks [0,3125) = fused user gather+ELU+GEMM; [3125,15625) = item gather.
__global__ __launch_bounds__(256, 4) void epilogue_kernel(
    const unsigned short* __restrict__ h_u, const unsigned short* __restrict__ h_i,
    const int* __restrict__ cnt, const int* __restrict__ bkt,
    const float* __restrict__ al_uu, const float* __restrict__ ar_uu,
    const float* __restrict__ al_iu, const float* __restrict__ ar_iu,
    const float* __restrict__ al_ui, const float* __restrict__ ar_ui,
    const unsigned short* __restrict__ Wok, const float* __restrict__ bo,
    float* __restrict__ out_u, float* __restrict__ out_i)
{
    __shared__ unsigned short gbuf[16 * HID];       // 4 KB (user path)
    __shared__ unsigned short ldsW[OUT_DIM * HID];  // 16 KB (user path)

    int tid  = threadIdx.x;
    int wave = tid >> 6;
    int lane = tid & 63;

    if (blockIdx.x >= NSTRIP) {
        // ---- item gather path ----
        int v = (blockIdx.x - NSTRIP) * 4 + wave;
        if (v >= N_ITEM) return;

        unsigned int hv = *(const unsigned int*)(h_i + (size_t)v * HID + lane * 2);

        int d = cnt[2 * N_USER + v];
        const int4* bq4 = (const int4*)(bkt + 2 * (size_t)N_USER * CAP + (size_t)v * CAP);
        int4 qa = bq4[0], qb = bq4[1];
        int idx[8] = {qa.x, qa.y, qa.z, qa.w, qb.x, qb.y, qb.z, qb.w};

        unsigned int rr[8];
        #pragma unroll
        for (int j = 0; j < 8; ++j) {
            int s = j < d ? idx[j] : v;
            rr[j] = *(const unsigned int*)(h_u + (size_t)s * HID + lane * 2);
        }
        float s0 = 0.f, s1 = 0.f;
        #pragma unroll
        for (int j = 0; j < 8; ++j) {
            float m = j < d ? 1.f : 0.f;
            s0 += m * bf2f((unsigned short)rr[j]);
            s1 += m * bf2f((unsigned short)(rr[j] >> 16));
        }
        if (d > 8) {
            int n = min(d, CAP);
            const int* bq = bkt + 2 * (size_t)N_USER * CAP + (size_t)v * CAP;
            for (int j = 8; j < n; ++j) {
                unsigned int u = *(const unsigned int*)(h_u + (size_t)bq[j] * HID + lane * 2);
                s0 += bf2f((unsigned short)u);
                s1 += bf2f((unsigned short)(u >> 16));
            }
        }

        float rscale = ar_ui[0] * (float)d;
        float o0 = elu_f(rscale * bf2f((unsigned short)hv) + al_ui[0] * s0);
        float o1 = elu_f(rscale * bf2f((unsigned short)(hv >> 16)) + al_ui[0] * s1);

        int r_pos = lane >> 2;
        int c0 = ((2 * lane) & 7) * 16 + r_pos;
        float* orow = out_i + (size_t)v * HID;
        orow[c0]      = o0;
        orow[c0 + 16] = o1;
        return;
    }

    // ---- fused user path ----
    int base = blockIdx.x * 16;

    #pragma unroll
    for (int it = 0; it < 4; ++it)
        ((int4*)ldsW)[it * 256 + tid] = ((const int4*)Wok)[it * 256 + tid];

    float aluu = al_uu[0], aruu = ar_uu[0], aliu = al_iu[0], ariu = ar_iu[0];

    #pragma unroll 1
    for (int q = 0; q < 4; ++q) {
        int vloc = wave * 4 + q;
        int v = base + vloc;

        unsigned int hv = *(const unsigned int*)(h_u + (size_t)v * HID + lane * 2);
        int d_uu = cnt[v];
        int d_iu = cnt[N_USER + v];

        const int4* b0 = (const int4*)(bkt + (size_t)v * CAP);
        const int4* b1 = (const int4*)(bkt + (size_t)N_USER * CAP + (size_t)v * CAP);
        int4 q0a = b0[0], q0b = b0[1];
        int4 q1a = b1[0], q1b = b1[1];
        int idx0[8] = {q0a.x, q0a.y, q0a.z, q0a.w, q0b.x, q0b.y, q0b.z, q0b.w};
        int idx1[8] = {q1a.x, q1a.y, q1a.z, q1a.w, q1b.x, q1b.y, q1b.z, q1b.w};

        unsigned int ru[8], ri[8];
        #pragma unroll
        for (int j = 0; j < 8; ++j) {
            int s = j < d_uu ? idx0[j] : v;
            ru[j] = *(const unsigned int*)(h_u + (size_t)s * HID + lane * 2);
        }
        #pragma unroll
        for (int j = 0; j < 8; ++j) {
            int s = j < d_iu ? idx1[j] : v;
            ri[j] = *(const unsigned int*)(h_i + (size_t)s * HID + lane * 2);
        }
        float s0u = 0.f, s1u = 0.f, s0i = 0.f, s1i = 0.f;
        #pragma unroll
        for (int j = 0; j < 8; ++j) {
            float mu = j < d_uu ? 1.f : 0.f;
            float mi = j < d_iu ? 1.f : 0.f;
            s0u += mu * bf2f((unsigned short)ru[j]);
            s1u += mu * bf2f((unsigned short)(ru[j] >> 16));
            s0i += mi * bf2f((unsigned short)ri[j]);
            s1i += mi * bf2f((unsigned short)(ri[j] >> 16));
        }
        if (d_uu > 8) {
            int n = min(d_uu, CAP);
            const int* bq = bkt + (size_t)v * CAP;
            for (int j = 8; j < n; ++j) {
                unsigned int u = *(const unsigned int*)(h_u + (size_t)bq[j] * HID + lane * 2);
                s0u += bf2f((unsigned short)u);
                s1u += bf2f((unsigned short)(u >> 16));
            }
        }
        if (d_iu > 8) {
            int n = min(d_iu, CAP);
            const int* bq = bkt + (size_t)N_USER * CAP + (size_t)v * CAP;
            for (int j = 8; j < n; ++j) {
                unsigned int u = *(const unsigned int*)(h_i + (size_t)bq[j] * HID + lane * 2);
                s0i += bf2f((unsigned short)u);
                s1i += bf2f((unsigned short)(u >> 16));
            }
        }

        float rscale = aruu * (float)d_uu + ariu * (float)d_iu;
        float acc0 = aluu * s0u + aliu * s0i + rscale * bf2f((unsigned short)hv);
        float acc1 = aluu * s1u + aliu * s1i + rscale * bf2f((unsigned short)(hv >> 16));

        unsigned int packed = cvt_pk_bf16(elu_f(acc0), elu_f(acc1));
        *(unsigned int*)((char*)gbuf + ((vloc * 256 + lane * 4) ^ ((vloc & 7) << 4))) = packed;
    }
    __syncthreads();

    if (wave == 0) {
        int r  = lane & 15;
        int kg = lane >> 4;

        bf16x8 a[4];
        #pragma unroll
        for (int kb = 0; kb < 4; ++kb)
            a[kb] = *(const bf16x8*)((const char*)gbuf +
                      (((r * 256) + kb * 64 + kg * 16) ^ ((r & 7) << 4)));

        const bf16x8* wl = (const bf16x8*)ldsW + lane;
        #pragma unroll
        for (int nt = 0; nt < 4; ++nt) {
            f32x4 c = {0.f, 0.f, 0.f, 0.f};
            #pragma unroll
            for (int kb = 0; kb < 4; ++kb)
                c = __builtin_amdgcn_mfma_f32_16x16x32_bf16(a[kb], wl[(nt * 4 + kb) * 64], c, 0, 0, 0);
            float bias = bo[nt * 16 + r];
            #pragma unroll
            for (int i = 0; i < 4; ++i)
                out_u[(size_t)(base + kg * 4 + i) * OUT_DIM + nt * 16 + r] = c[i] + bias;
        }
    }
}

extern "C" void kernel_launch(void* const* d_in, const int* in_sizes, int n_in,
                              void* d_out, int out_size, void* d_ws, size_t ws_size,
                              hipStream_t stream)
{
    const float* x_user = (const float*)d_in[0];
    const float* x_item = (const float*)d_in[1];
    const float* W_proj = (const float*)d_in[2];
    const float* b_proj = (const float*)d_in[3];
    const float* al_uu  = (const float*)d_in[4];
    const float* ar_uu  = (const float*)d_in[5];
    const float* al_iu  = (const float*)d_in[6];
    const float* ar_iu  = (const float*)d_in[7];
    const float* al_ui  = (const float*)d_in[8];
    const float* ar_ui  = (const float*)d_in[9];
    const float* W_out  = (const float*)d_in[10];
    const float* b_out  = (const float*)d_in[11];
    const int* edges_uu = (const int*)d_in[12];
    const int* edges_iu = (const int*)d_in[13];
    const int* edges_ui = (const int*)d_in[14];

    char* ws = (char*)d_ws;
    unsigned short* h_u = (unsigned short*)(ws);                   // 12,800,000
    unsigned short* h_i = (unsigned short*)(ws + 12800000);        // 12,800,000
    unsigned short* Wpk = (unsigned short*)(ws + 25600000);        //    524,288 (8 copies)
    unsigned short* Wok = (unsigned short*)(ws + 26124288);        //     16,384
    int* cnt            = (int*)(ws + 26140672);                   //    600,000 (3 x 50000)
    int* bkt            = (int*)(ws + 26740672);                   // 19,200,000 (3 x 50000 x 32)

    float* out_u = (float*)d_out;
    float* out_i = out_u + (size_t)N_USER * OUT_DIM;

    dim3 blk(256);
    // pack W (blocks 0..19) + zero cnt (blocks 20..605)
    pack_w_kernel<<<dim3(606), blk, 0, stream>>>(W_proj, W_out, Wpk, Wok, cnt);

    // proj (blocks 0..390) + edge fill (blocks 391..978) in one dispatch
    proj_kernel<<<dim3(PROJ_GRID + FILL_GRID), dim3(1024), 0, stream>>>(
        x_user, x_item, Wpk, b_proj, h_u, h_i,
        edges_uu, edges_iu, edges_ui, cnt, bkt);

    epilogue_kernel<<<dim3(NSTRIP + 12500), blk, 0, stream>>>(
        h_u, h_i, cnt, bkt, al_uu, ar_uu, al_iu, ar_iu, al_ui, ar_ui,
        Wok, b_out, out_u, out_i);
}

// Round 13
// 93.835 us; speedup vs baseline: 1.4008x; 1.0367x over previous
//
#include <hip/hip_runtime.h>
#include <hip/hip_bf16.h>

typedef short bf16x8 __attribute__((ext_vector_type(8)));
typedef float f32x4 __attribute__((ext_vector_type(4)));

#define N_USER 50000
#define N_ITEM 50000
#define IN_DIM 256
#define HID 128
#define OUT_DIM 64
#define NEDGE 200000
#define CAP 32
#define NSTRIP 3125    // 50000/16
#define FILL_GRID 64   // grid-stride fill blocks (64 x 1024 threads, ~9 edges/thread)
#define PROJ_GRID 391  // ceil(6250 strips / 16 waves)

__device__ __forceinline__ float bf2f(unsigned short u) {
    union { unsigned int i; float f; } v; v.i = ((unsigned int)u) << 16; return v.f;
}
__device__ __forceinline__ unsigned short f2bf(float f) {
    union { float f; unsigned int i; } v; v.f = f;
    return (unsigned short)((v.i + 0x7fffu + ((v.i >> 16) & 1u)) >> 16);
}
__device__ __forceinline__ unsigned int cvt_pk_bf16(float a, float b) {
    unsigned int r;
    asm("v_cvt_pk_bf16_f32 %0, %1, %2" : "=v"(r) : "v"(a), "v"(b));
    return r;
}
__device__ __forceinline__ float elu_f(float x) {
    return x > 0.f ? x : (__expf(x) - 1.f);
}

// ---- pack weights (frag order) + zero cnt, one launch ----
__global__ __launch_bounds__(256) void pack_w_kernel(
    const float* __restrict__ Wp, const float* __restrict__ Wo,
    unsigned short* __restrict__ Wpk, unsigned short* __restrict__ Wok,
    int* __restrict__ cnt)
{
    int bid = blockIdx.x;
    if (bid >= 20) {
        int idx = (bid - 20) * 256 + threadIdx.x;
        if (idx < 3 * N_USER) cnt[idx] = 0;
        return;
    }
    int t = bid * 256 + threadIdx.x;
    if (t < 4096) {
        int lane = t & 63, kb = (t >> 6) & 7, nt = t >> 9;
        int r = lane & 15, kg = lane >> 4;
        unsigned short o[8];
        #pragma unroll
        for (int j = 0; j < 8; ++j)
            o[j] = f2bf(Wp[(size_t)(kb * 32 + kg * 8 + j) * HID + nt * 16 + r]);
        for (int cp = 0; cp < 8; ++cp) {
            #pragma unroll
            for (int j = 0; j < 8; ++j) Wpk[cp * 32768 + t * 8 + j] = o[j];
        }
    } else if (t < 4096 + 1024) {
        int q = t - 4096;
        int lane = q & 63, kb = (q >> 6) & 3, nt = q >> 8;
        int r = lane & 15, kg = lane >> 4;
        unsigned short o[8];
        #pragma unroll
        for (int j = 0; j < 8; ++j)
            o[j] = f2bf(Wo[(size_t)(j * 16 + kb * 4 + kg) * OUT_DIM + nt * 16 + r]);
        #pragma unroll
        for (int j = 0; j < 8; ++j) Wok[q * 8 + j] = o[j];
    }
}

// Blocks [0,64): grid-stride edge bucket-fill (all 455 blocks co-resident -> fill
// overlaps proj's staging phase instead of forming a serial tail).
// Blocks [64,455): fused projection (unchanged math).
__global__ __launch_bounds__(1024, 4) void proj_kernel(
    const float* __restrict__ x_u, const float* __restrict__ x_i,
    const unsigned short* __restrict__ Wpk, const float* __restrict__ b,
    unsigned short* __restrict__ h_u, unsigned short* __restrict__ h_i,
    const int* __restrict__ e_uu, const int* __restrict__ e_iu,
    const int* __restrict__ e_ui, int* __restrict__ cnt, int* __restrict__ bkt)
{
    __shared__ unsigned short lds[HID * IN_DIM];  // 65536 B, packed frag order

    int tid = threadIdx.x;
    int bid = blockIdx.x;

    if (bid < FILL_GRID) {
        // ---- edge bucket-fill path (grid-stride, ~9 independent chains/thread) ----
        for (int g = bid * 1024 + tid; g < 3 * NEDGE; g += FILL_GRID * 1024) {
            int rel = g >= 2 * NEDGE ? 2 : (g >= NEDGE ? 1 : 0);
            const int* e = rel == 0 ? e_uu : (rel == 1 ? e_iu : e_ui);
            int eid = g - rel * NEDGE;
            int2 sd = *(const int2*)(e + 2 * (size_t)eid);
            int* c  = cnt + (size_t)rel * N_USER;
            int* bk = bkt + (size_t)rel * N_USER * CAP;
            int slot = atomicAdd(&c[sd.y], 1);
            if (slot < CAP) bk[(size_t)sd.y * CAP + slot] = sd.x;
        }
        return;
    }
    bid -= FILL_GRID;

    // ---- projection path ----
    const int4* wsel = (const int4*)(Wpk + (size_t)(bid & 7) * 32768);
    int4 w0 = wsel[tid];
    int4 w1 = wsel[1024 + tid];
    int4 w2 = wsel[2048 + tid];
    int4 w3 = wsel[3072 + tid];

    int wave = tid >> 6;
    int lane = tid & 63;
    int strip = bid * 16 + wave;
    strip = min(strip, 2 * NSTRIP - 1);   // clamp: duplicate writes are identical
    const float* x = x_u;
    unsigned short* h = h_u;
    if (strip >= NSTRIP) { strip -= NSTRIP; x = x_i; h = h_i; }

    int row0 = strip * 16;
    int r  = lane & 15;
    int kg = lane >> 4;

    bf16x8 a[8];
    const float* xrow = x + (size_t)(row0 + r) * IN_DIM;
    #pragma unroll
    for (int kb = 0; kb < 8; ++kb) {
        float4 v0 = *(const float4*)(xrow + kb * 32 + kg * 8);
        float4 v1 = *(const float4*)(xrow + kb * 32 + kg * 8 + 4);
        unsigned int* au = (unsigned int*)&a[kb];
        au[0] = cvt_pk_bf16(v0.x, v0.y);
        au[1] = cvt_pk_bf16(v0.z, v0.w);
        au[2] = cvt_pk_bf16(v1.x, v1.y);
        au[3] = cvt_pk_bf16(v1.z, v1.w);
    }

    ((int4*)lds)[tid]        = w0;
    ((int4*)lds)[1024 + tid] = w1;
    ((int4*)lds)[2048 + tid] = w2;
    ((int4*)lds)[3072 + tid] = w3;
    __syncthreads();

    float bias[8];
    #pragma unroll
    for (int nt = 0; nt < 8; ++nt) bias[nt] = b[nt * 16 + r];

    f32x4 c[8];
    #pragma unroll
    for (int nt = 0; nt < 8; ++nt) c[nt] = (f32x4){0.f, 0.f, 0.f, 0.f};

    const bf16x8* wl = (const bf16x8*)lds + lane;
    #pragma unroll
    for (int nt = 0; nt < 8; ++nt) {
        #pragma unroll
        for (int kb = 0; kb < 8; ++kb)
            c[nt] = __builtin_amdgcn_mfma_f32_16x16x32_bf16(a[kb], wl[(nt * 8 + kb) * 64], c[nt], 0, 0, 0);
    }

    // packed store: row rr, P-positions pos = r*8+nt (col = nt*16+r), 16B per lane
    #pragma unroll
    for (int i = 0; i < 4; ++i) {
        uint4 val;
        val.x = cvt_pk_bf16(c[0][i] + bias[0], c[1][i] + bias[1]);
        val.y = cvt_pk_bf16(c[2][i] + bias[2], c[3][i] + bias[3]);
        val.z = cvt_pk_bf16(c[4][i] + bias[4], c[5][i] + bias[5]);
        val.w = cvt_pk_bf16(c[6][i] + bias[6], c[7][i] + bias[7]);
        *(uint4*)(h + (size_t)(row0 + kg * 4 + i) * HID + r * 8) = val;
    }
}

// Merged epilogue: blocks [0,3125) = fused user gather+ELU+GEMM; [3125,15625) = item gather.
__global__ __launch_bounds__(256, 4) void epilogue_kernel(
    const unsigned short* __restrict__ h_u, const unsigned short* __restrict__ h_i,
    const int* __restrict__ cnt, const int* __restrict__ bkt,
    const float* __restrict__ al_uu, const float* __restrict__ ar_uu,
    const float* __restrict__ al_iu, const float* __restrict__ ar_iu,
    const float* __restrict__ al_ui, const float* __restrict__ ar_ui,
    const unsigned short* __restrict__ Wok, const float* __restrict__ bo,
    float* __restrict__ out_u, float* __restrict__ out_i)
{
    __shared__ unsigned short gbuf[16 * HID];       // 4 KB (user path)
    __shared__ unsigned short ldsW[OUT_DIM * HID];  // 16 KB (user path)

    int tid  = threadIdx.x;
    int wave = tid >> 6;
    int lane = tid & 63;

    if (blockIdx.x >= NSTRIP) {
        // ---- item gather path ----
        int v = (blockIdx.x - NSTRIP) * 4 + wave;
        if (v >= N_ITEM) return;

        unsigned int hv = *(const unsigned int*)(h_i + (size_t)v * HID + lane * 2);

        int d = cnt[2 * N_USER + v];
        const int4* bq4 = (const int4*)(bkt + 2 * (size_t)N_USER * CAP + (size_t)v * CAP);
        int4 qa = bq4[0], qb = bq4[1];
        int idx[8] = {qa.x, qa.y, qa.z, qa.w, qb.x, qb.y, qb.z, qb.w};

        unsigned int rr[8];
        #pragma unroll
        for (int j = 0; j < 8; ++j) {
            int s = j < d ? idx[j] : v;
            rr[j] = *(const unsigned int*)(h_u + (size_t)s * HID + lane * 2);
        }
        float s0 = 0.f, s1 = 0.f;
        #pragma unroll
        for (int j = 0; j < 8; ++j) {
            float m = j < d ? 1.f : 0.f;
            s0 += m * bf2f((unsigned short)rr[j]);
            s1 += m * bf2f((unsigned short)(rr[j] >> 16));
        }
        if (d > 8) {
            int n = min(d, CAP);
            const int* bq = bkt + 2 * (size_t)N_USER * CAP + (size_t)v * CAP;
            for (int j = 8; j < n; ++j) {
                unsigned int u = *(const unsigned int*)(h_u + (size_t)bq[j] * HID + lane * 2);
                s0 += bf2f((unsigned short)u);
                s1 += bf2f((unsigned short)(u >> 16));
            }
        }

        float rscale = ar_ui[0] * (float)d;
        float o0 = elu_f(rscale * bf2f((unsigned short)hv) + al_ui[0] * s0);
        float o1 = elu_f(rscale * bf2f((unsigned short)(hv >> 16)) + al_ui[0] * s1);

        int r_pos = lane >> 2;
        int c0 = ((2 * lane) & 7) * 16 + r_pos;
        float* orow = out_i + (size_t)v * HID;
        orow[c0]      = o0;
        orow[c0 + 16] = o1;
        return;
    }

    // ---- fused user path ----
    int base = blockIdx.x * 16;

    #pragma unroll
    for (int it = 0; it < 4; ++it)
        ((int4*)ldsW)[it * 256 + tid] = ((const int4*)Wok)[it * 256 + tid];

    float aluu = al_uu[0], aruu = ar_uu[0], aliu = al_iu[0], ariu = ar_iu[0];

    #pragma unroll 1
    for (int q = 0; q < 4; ++q) {
        int vloc = wave * 4 + q;
        int v = base + vloc;

        unsigned int hv = *(const unsigned int*)(h_u + (size_t)v * HID + lane * 2);
        int d_uu = cnt[v];
        int d_iu = cnt[N_USER + v];

        const int4* b0 = (const int4*)(bkt + (size_t)v * CAP);
        const int4* b1 = (const int4*)(bkt + (size_t)N_USER * CAP + (size_t)v * CAP);
        int4 q0a = b0[0], q0b = b0[1];
        int4 q1a = b1[0], q1b = b1[1];
        int idx0[8] = {q0a.x, q0a.y, q0a.z, q0a.w, q0b.x, q0b.y, q0b.z, q0b.w};
        int idx1[8] = {q1a.x, q1a.y, q1a.z, q1a.w, q1b.x, q1b.y, q1b.z, q1b.w};

        unsigned int ru[8], ri[8];
        #pragma unroll
        for (int j = 0; j < 8; ++j) {
            int s = j < d_uu ? idx0[j] : v;
            ru[j] = *(const unsigned int*)(h_u + (size_t)s * HID + lane * 2);
        }
        #pragma unroll
        for (int j = 0; j < 8; ++j) {
            int s = j < d_iu ? idx1[j] : v;
            ri[j] = *(const unsigned int*)(h_i + (size_t)s * HID + lane * 2);
        }
        float s0u = 0.f, s1u = 0.f, s0i = 0.f, s1i = 0.f;
        #pragma unroll
        for (int j = 0; j < 8; ++j) {
            float mu = j < d_uu ? 1.f : 0.f;
            float mi = j < d_iu ? 1.f : 0.f;
            s0u += mu * bf2f((unsigned short)ru[j]);
            s1u += mu * bf2f((unsigned short)(ru[j] >> 16));
            s0i += mi * bf2f((unsigned short)ri[j]);
            s1i += mi * bf2f((unsigned short)(ri[j] >> 16));
        }
        if (d_uu > 8) {
            int n = min(d_uu, CAP);
            const int* bq = bkt + (size_t)v * CAP;
            for (int j = 8; j < n; ++j) {
                unsigned int u = *(const unsigned int*)(h_u + (size_t)bq[j] * HID + lane * 2);
                s0u += bf2f((unsigned short)u);
                s1u += bf2f((unsigned short)(u >> 16));
            }
        }
        if (d_iu > 8) {
            int n = min(d_iu, CAP);
            const int* bq = bkt + (size_t)N_USER * CAP + (size_t)v * CAP;
            for (int j = 8; j < n; ++j) {
                unsigned int u = *(const unsigned int*)(h_i + (size_t)bq[j] * HID + lane * 2);
                s0i += bf2f((unsigned short)u);
                s1i += bf2f((unsigned short)(u >> 16));
            }
        }

        float rscale = aruu * (float)d_uu + ariu * (float)d_iu;
        float acc0 = aluu * s0u + aliu * s0i + rscale * bf2f((unsigned short)hv);
        float acc1 = aluu * s1u + aliu * s1i + rscale * bf2f((unsigned short)(hv >> 16));

        unsigned int packed = cvt_pk_bf16(elu_f(acc0), elu_f(acc1));
        *(unsigned int*)((char*)gbuf + ((vloc * 256 + lane * 4) ^ ((vloc & 7) << 4))) = packed;
    }
    __syncthreads();

    if (wave == 0) {
        int r  = lane & 15;
        int kg = lane >> 4;

        bf16x8 a[4];
        #pragma unroll
        for (int kb = 0; kb < 4; ++kb)
            a[kb] = *(const bf16x8*)((const char*)gbuf +
                      (((r * 256) + kb * 64 + kg * 16) ^ ((r & 7) << 4)));

        const bf16x8* wl = (const bf16x8*)ldsW + lane;
        #pragma unroll
        for (int nt = 0; nt < 4; ++nt) {
            f32x4 c = {0.f, 0.f, 0.f, 0.f};
            #pragma unroll
            for (int kb = 0; kb < 4; ++kb)
                c = __builtin_amdgcn_mfma_f32_16x16x32_bf16(a[kb], wl[(nt * 4 + kb) * 64], c, 0, 0, 0);
            float bias = bo[nt * 16 + r];
            #pragma unroll
            for (int i = 0; i < 4; ++i)
                out_u[(size_t)(base + kg * 4 + i) * OUT_DIM + nt * 16 + r] = c[i] + bias;
        }
    }
}

extern "C" void kernel_launch(void* const* d_in, const int* in_sizes, int n_in,
                              void* d_out, int out_size, void* d_ws, size_t ws_size,
                              hipStream_t stream)
{
    const float* x_user = (const float*)d_in[0];
    const float* x_item = (const float*)d_in[1];
    const float* W_proj = (const float*)d_in[2];
    const float* b_proj = (const float*)d_in[3];
    const float* al_uu  = (const float*)d_in[4];
    const float* ar_uu  = (const float*)d_in[5];
    const float* al_iu  = (const float*)d_in[6];
    const float* ar_iu  = (const float*)d_in[7];
    const float* al_ui  = (const float*)d_in[8];
    const float* ar_ui  = (const float*)d_in[9];
    const float* W_out  = (const float*)d_in[10];
    const float* b_out  = (const float*)d_in[11];
    const int* edges_uu = (const int*)d_in[12];
    const int* edges_iu = (const int*)d_in[13];
    const int* edges_ui = (const int*)d_in[14];

    char* ws = (char*)d_ws;
    unsigned short* h_u = (unsigned short*)(ws);                   // 12,800,000
    unsigned short* h_i = (unsigned short*)(ws + 12800000);        // 12,800,000
    unsigned short* Wpk = (unsigned short*)(ws + 25600000);        //    524,288 (8 copies)
    unsigned short* Wok = (unsigned short*)(ws + 26124288);        //     16,384
    int* cnt            = (int*)(ws + 26140672);                   //    600,000 (3 x 50000)
    int* bkt            = (int*)(ws + 26740672);                   // 19,200,000 (3 x 50000 x 32)

    float* out_u = (float*)d_out;
    float* out_i = out_u + (size_t)N_USER * OUT_DIM;

    dim3 blk(256);
    // pack W (blocks 0..19) + zero cnt (blocks 20..605)
    pack_w_kernel<<<dim3(606), blk, 0, stream>>>(W_proj, W_out, Wpk, Wok, cnt);

    // fill (blocks 0..63, grid-stride) + proj (blocks 64..454) in one dispatch;
    // 455 blocks <= 512 co-residency slots -> fill overlaps proj instead of tailing.
    proj_kernel<<<dim3(FILL_GRID + PROJ_GRID), dim3(1024), 0, stream>>>(
        x_user, x_item, Wpk, b_proj, h_u, h_i,
        edges_uu, edges_iu, edges_ui, cnt, bkt);

    epilogue_kernel<<<dim3(NSTRIP + 12500), blk, 0, stream>>>(
        h_u, h_i, cnt, bkt, al_uu, ar_uu, al_iu, ar_iu, al_ui, ar_ui,
        Wok, b_out, out_u, out_i);
}